// Round 6
// baseline (1461.769 us; speedup 1.0000x reference)
//
#include <hip/hip_runtime.h>
#include <hip/hip_bf16.h>
#include <math.h>

#define DD   64
#define DD2  128
#define NN   20000
#define RR   24
#define SS   3
#define EE   60000
#define BB   8
#define KK   101
#define HLENN 50
#define MROWS 20024   // 20000 nodes + 24 appended rel rows

// ---------------------------------------------------------------------------
// Full CSR build + degree for all 3 snapshots. 3 blocks (one per snapshot),
// 1024 threads, 80KB LDS histogram. Replaces memset+hist+scan+place.
__global__ __launch_bounds__(1024) void csr_kernel(
        const int* __restrict__ src, const int* __restrict__ dst,
        const int* __restrict__ et,
        int* __restrict__ rowptr,   // [3][NN+1]
        int* __restrict__ colp,     // [3][EE]  src | et<<16, grouped by dst
        int* __restrict__ deg) {    // [3][NN]  in+out degree
    __shared__ int lh[NN];
    __shared__ int sp[1024];
    int s = blockIdx.x, t = threadIdx.x;
    const int* ps = src + s * EE;
    const int* pd = dst + s * EE;
    const int* pt = et + s * EE;
    int* rp = rowptr + s * (NN + 1);
    // dst histogram
    for (int i = t; i < NN; i += 1024) lh[i] = 0;
    __syncthreads();
    for (int e = t; e < EE; e += 1024) atomicAdd(&lh[pd[e]], 1);
    __syncthreads();
    // exclusive scan -> rowptr; lh becomes cursor
    int base = t * 20, sum = 0;
    for (int i = 0; i < 20; ++i) { int idx = base + i; if (idx < NN) sum += lh[idx]; }
    sp[t] = sum;
    __syncthreads();
    for (int off = 1; off < 1024; off <<= 1) {
        int v = (t >= off) ? sp[t - off] : 0;
        __syncthreads();
        sp[t] += v;
        __syncthreads();
    }
    int run = sp[t] - sum;
    for (int i = 0; i < 20; ++i) {
        int idx = base + i;
        if (idx < NN) { rp[idx] = run; int c = lh[idx]; lh[idx] = run; run += c; }
    }
    if (t == 1023) rp[NN] = sp[1023];
    __syncthreads();
    // place edges
    for (int e = t; e < EE; e += 1024) {
        int pos = atomicAdd(&lh[pd[e]], 1);
        colp[s * EE + pos] = ps[e] | (pt[e] << 16);
    }
    __syncthreads();
    // src histogram -> deg = out + in
    for (int i = t; i < NN; i += 1024) lh[i] = 0;
    __syncthreads();
    for (int e = t; e < EE; e += 1024) atomicAdd(&lh[ps[e]], 1);
    __syncthreads();
    for (int i = t; i < NN; i += 1024)
        deg[s * NN + i] = lh[i] + (rp[i + 1] - rp[i]);
}

// ---------------------------------------------------------------------------
// Per-snapshot stage 1: init (deg*poi, gated for s>0) fused with the layer-0
// GEMM pair: y = A@Wt, z = A@Wb where A = [init rows | rel0 rows].
// 313 blocks x 256 threads; 64 rows per block.
__global__ __launch_bounds__(256) void initgemm_kernel(
        const float* __restrict__ poi, const int* __restrict__ deg,
        const float* __restrict__ gate_W, const float* __restrict__ gate_b,
        const float* __restrict__ xprev, const float* __restrict__ rel,
        const float* __restrict__ W,   // [128][64]: rows 0..63 Wt, 64..127 Wb
        float* __restrict__ initb, float* __restrict__ y, float* __restrict__ z,
        int use_gate) {
    __shared__ float sGW[64][64];
    __shared__ float sA[64][68];
    __shared__ float sBt[64][68];
    __shared__ float sBb[64][68];
    __shared__ float srow[4][64];
    int tid = threadIdx.x;
    int li = tid >> 6, d = tid & 63;
    int row0 = blockIdx.x * 64;
    if (use_gate) {
        for (int i = tid; i < 64 * 64; i += 256) sGW[i >> 6][i & 63] = gate_W[i];
        __syncthreads();
    }
    float gb = use_gate ? gate_b[d] : 0.f;
    for (int it = 0; it < 16; ++it) {
        int rl = it * 4 + li;
        int row = row0 + rl;
        float iv;
        if (row < NN)           iv = (float)deg[row] * poi[(size_t)row * 64 + d];
        else if (row < MROWS)   iv = rel[(row - NN) * 64 + d];
        else                    iv = 0.f;
        if (use_gate) {
            float ov = (row < NN) ? xprev[(size_t)row * 64 + d] : 0.f;
            srow[li][d] = ov;
            __syncthreads();
            float acc = gb;
            #pragma unroll
            for (int k = 0; k < 64; ++k) acc += srow[li][k] * sGW[k][d];
            float g = 1.f / (1.f + expf(-acc));
            if (row < NN) iv = iv * g + (1.f - g) * ov;
            __syncthreads();
        }
        sA[rl][d] = iv;
        if (row < NN) initb[(size_t)row * 64 + d] = iv;
    }
    for (int i = tid; i < 64 * 64; i += 256) {
        sBt[i >> 6][i & 63] = W[i];
        sBb[i >> 6][i & 63] = W[64 * 64 + i];
    }
    __syncthreads();
    int tr = tid >> 4, tc = tid & 15;
    float accY[4][4] = {{0.f}}, accZ[4][4] = {{0.f}};
    #pragma unroll 16
    for (int k = 0; k < 64; ++k) {
        float4 bt = *(const float4*)&sBt[k][tc * 4];
        float4 bz = *(const float4*)&sBb[k][tc * 4];
        #pragma unroll
        for (int i = 0; i < 4; ++i) {
            float a = sA[tr * 4 + i][k];
            accY[i][0] += a * bt.x; accY[i][1] += a * bt.y; accY[i][2] += a * bt.z; accY[i][3] += a * bt.w;
            accZ[i][0] += a * bz.x; accZ[i][1] += a * bz.y; accZ[i][2] += a * bz.z; accZ[i][3] += a * bz.w;
        }
    }
    #pragma unroll
    for (int i = 0; i < 4; ++i) {
        int row = row0 + tr * 4 + i;
        if (row < MROWS) {
            *(float4*)(y + (size_t)row * 64 + tc * 4) = make_float4(accY[i][0], accY[i][1], accY[i][2], accY[i][3]);
            *(float4*)(z + (size_t)row * 64 + tc * 4) = make_float4(accZ[i][0], accZ[i][1], accZ[i][2], accZ[i][3]);
        }
    }
}

// ---------------------------------------------------------------------------
// Per-snapshot stage 2: fin of layer 0 (x1 = relu(z + b + sum(y[src]+relW[et])))
// fused with the layer-1 GEMM pair: y2 = [x1|rel1]@Wt1, z2 = init@Wb1.
__global__ __launch_bounds__(256) void fingemm_kernel(
        const float* __restrict__ y, const float* __restrict__ z,
        const int* __restrict__ rp, const int* __restrict__ cp,
        const float* __restrict__ bias0, const float* __restrict__ rel1,
        const float* __restrict__ W1,  // layer-1 [128][64]
        const float* __restrict__ initb,
        float* __restrict__ y2, float* __restrict__ z2) {
    __shared__ float srelW[24][64];
    __shared__ float sA[64][68];
    __shared__ float sAi[64][68];
    __shared__ float sBt[64][68];
    __shared__ float sBb[64][68];
    int tid = threadIdx.x;
    int li = tid >> 6, d = tid & 63;
    int row0 = blockIdx.x * 64;
    for (int i = tid; i < 24 * 64; i += 256) srelW[i >> 6][i & 63] = y[(size_t)NN * 64 + i];
    for (int i = tid; i < 64 * 64; i += 256) {
        sBt[i >> 6][i & 63] = W1[i];
        sBb[i >> 6][i & 63] = W1[64 * 64 + i];
    }
    for (int i = tid; i < 64 * 16; i += 256) {
        int r = i >> 4, cq = i & 15;
        int row = row0 + r;
        float4 v = make_float4(0.f, 0.f, 0.f, 0.f);
        if (row < NN) v = *(const float4*)(initb + (size_t)row * 64 + cq * 4);
        *(float4*)&sAi[r][cq * 4] = v;
    }
    __syncthreads();
    float bb0 = bias0[d];
    for (int it = 0; it < 16; ++it) {
        int rl = it * 4 + li;
        int row = row0 + rl;
        float val = 0.f;
        if (row < NN) {
            float acc = z[(size_t)row * 64 + d] + bb0;
            int e0 = rp[row], e1 = rp[row + 1];
            for (int e = e0; e < e1; ++e) {
                int pack = cp[e];
                acc += y[(size_t)(pack & 0xFFFF) * 64 + d] + srelW[pack >> 16][d];
            }
            val = fmaxf(acc, 0.f);
        } else if (row < MROWS) {
            val = rel1[(row - NN) * 64 + d];
        }
        sA[rl][d] = val;
    }
    __syncthreads();
    int tr = tid >> 4, tc = tid & 15;
    float accY[4][4] = {{0.f}}, accZ[4][4] = {{0.f}};
    #pragma unroll 16
    for (int k = 0; k < 64; ++k) {
        float4 bt = *(const float4*)&sBt[k][tc * 4];
        float4 bz = *(const float4*)&sBb[k][tc * 4];
        #pragma unroll
        for (int i = 0; i < 4; ++i) {
            float a  = sA[tr * 4 + i][k];
            float ai = sAi[tr * 4 + i][k];
            accY[i][0] += a * bt.x;  accY[i][1] += a * bt.y;  accY[i][2] += a * bt.z;  accY[i][3] += a * bt.w;
            accZ[i][0] += ai * bz.x; accZ[i][1] += ai * bz.y; accZ[i][2] += ai * bz.z; accZ[i][3] += ai * bz.w;
        }
    }
    #pragma unroll
    for (int i = 0; i < 4; ++i) {
        int row = row0 + tr * 4 + i;
        if (row < MROWS) {
            *(float4*)(y2 + (size_t)row * 64 + tc * 4) = make_float4(accY[i][0], accY[i][1], accY[i][2], accY[i][3]);
            *(float4*)(z2 + (size_t)row * 64 + tc * 4) = make_float4(accZ[i][0], accZ[i][1], accZ[i][2], accZ[i][3]);
        }
    }
}

// ---------------------------------------------------------------------------
// Per-snapshot stage 3: final fin of layer 1 -> snapshot output x (xA).
__global__ __launch_bounds__(256) void fin_kernel(
        const float* __restrict__ y, const float* __restrict__ z,
        const int* __restrict__ rowptr, const int* __restrict__ colp,
        const float* __restrict__ bias, float* __restrict__ xout) {
    __shared__ float srelW[24][64];
    int tid = threadIdx.x;
    for (int i = tid; i < 24 * 64; i += 256) srelW[i >> 6][i & 63] = y[(size_t)NN * 64 + i];
    int d = tid & 63, w = tid >> 6;
    float bb = bias[d];
    __syncthreads();
    int base = blockIdx.x * 16 + w * 4;
    for (int n = 0; n < 4; ++n) {
        int node = base + n;
        float acc = z[(size_t)node * 64 + d] + bb;
        int e0 = rowptr[node], e1 = rowptr[node + 1];
        for (int e = e0; e < e1; ++e) {
            int pack = colp[e];
            acc += y[(size_t)(pack & 0xFFFF) * 64 + d] + srelW[pack >> 16][d];
        }
        xout[(size_t)node * 64 + d] = fmaxf(acc, 0.f);
    }
}

// ---------------------------------------------------------------------------
// Whole post-GNN pipeline: query chain + history gather + 2 transformer
// layers + sequence mean. One block per batch row, 512 threads, ~145KB LDS.
__global__ __launch_bounds__(512) void tf_kernel(
        const float* __restrict__ feature, const float* __restrict__ query_emb,
        const int* __restrict__ r_index, const float* __restrict__ g_time_emb,
        const int* __restrict__ g_time, const float* __restrict__ g_lin_W,
        const float* __restrict__ g_lin_b, const int* __restrict__ history_poi,
        const float* __restrict__ hte,
        const float* __restrict__ tf_Wqkv, const float* __restrict__ tf_Wo,
        const float* __restrict__ tf_ln1, const float* __restrict__ tf_ln2,
        const float* __restrict__ tf_W1, const float* __restrict__ tf_b1,
        const float* __restrict__ tf_W2, const float* __restrict__ tf_b2,
        float* __restrict__ flab) {
    __shared__ float sxseq[HLENN][128];   // 25.6 KB
    __shared__ float sbig[25600];         // 102.4 KB (qkv | aout | h)
    __shared__ float ss[2][HLENN][HLENN]; // 20 KB
    __shared__ float sq[64], sq2[64];
    __shared__ float smean[HLENN], svar[HLENN];
    int b = blockIdx.x, tid = threadIdx.x;
    // ---- query chain (3 iterations of (q+time)@W + b) ----
    if (tid < 64) sq2[tid] = query_emb[r_index[b] * 64 + tid];
    __syncthreads();
    for (int s = 0; s < SS; ++s) {
        if (tid < 64) sq[tid] = sq2[tid] + g_time_emb[g_time[s] * 64 + tid];
        __syncthreads();
        float acc = 0.f;
        if (tid < 64) {
            acc = g_lin_b[tid];
            #pragma unroll 8
            for (int k = 0; k < 64; ++k) acc += sq[k] * g_lin_W[k * 64 + tid];
        }
        __syncthreads();
        if (tid < 64) sq2[tid] = acc;
        __syncthreads();
    }
    // ---- xseq build ----
    for (int p = tid; p < HLENN * 128; p += 512) {
        int t = p >> 7, c = p & 127;
        float v = (c < 64) ? feature[(size_t)history_poi[b * HLENN + t] * 64 + c]
                           : sq2[c - 64];
        sxseq[t][c] = v + hte[(b * HLENN + t) * 128 + c];
    }
    __syncthreads();
    // ---- transformer layers ----
    for (int l = 0; l < 2; ++l) {
        const float* Wqkv = tf_Wqkv + l * 128 * 384;
        const float* Wo   = tf_Wo   + l * 128 * 128;
        const float* W1   = tf_W1   + l * 128 * 512;
        const float* b1   = tf_b1   + l * 512;
        const float* W2   = tf_W2   + l * 512 * 128;
        const float* b2   = tf_b2   + l * 128;
        const float* ln1  = tf_ln1  + l * 256;
        const float* ln2  = tf_ln2  + l * 256;
        // qkv: sbig[0..19200) = xseq @ Wqkv
        for (int p = tid; p < HLENN * 384; p += 512) {
            int t = p / 384, j = p % 384;
            float acc = 0.f;
            #pragma unroll 8
            for (int k = 0; k < 128; ++k) acc += sxseq[t][k] * Wqkv[k * 384 + j];
            sbig[t * 384 + j] = acc;
        }
        __syncthreads();
        // scores
        for (int p = tid; p < 2 * HLENN * HLENN; p += 512) {
            int h = p / 2500, r = (p / 50) % 50, j = p % 50;
            float acc = 0.f;
            #pragma unroll 8
            for (int k = 0; k < 64; ++k)
                acc += sbig[r * 384 + h * 64 + k] * sbig[j * 384 + 128 + h * 64 + k];
            ss[h][r][j] = acc * 0.125f;
        }
        __syncthreads();
        // softmax over 100 (h, row) pairs
        if (tid < 2 * HLENN) {
            int h = tid / HLENN, r = tid % HLENN;
            float m = -1e30f;
            for (int j = 0; j < HLENN; ++j) m = fmaxf(m, ss[h][r][j]);
            float sum = 0.f;
            for (int j = 0; j < HLENN; ++j) { float e = expf(ss[h][r][j] - m); ss[h][r][j] = e; sum += e; }
            float inv = 1.f / sum;
            for (int j = 0; j < HLENN; ++j) ss[h][r][j] *= inv;
        }
        __syncthreads();
        // PV -> sbig[19200 + p) (v region is [*384+256..), disjoint)
        for (int p = tid; p < HLENN * 128; p += 512) {
            int t = p >> 7, c = p & 127, h = c >> 6, cc = c & 63;
            float acc = 0.f;
            for (int j = 0; j < HLENN; ++j)
                acc += ss[h][t][j] * sbig[j * 384 + 256 + h * 64 + cc];
            sbig[19200 + p] = acc;
        }
        __syncthreads();
        // o @ Wo + residual -> pre-LN into sbig[0..6400) (qkv dead)
        for (int p = tid; p < HLENN * 128; p += 512) {
            int t = p >> 7, c = p & 127;
            float acc = sxseq[t][c];
            #pragma unroll 8
            for (int k = 0; k < 128; ++k) acc += sbig[19200 + t * 128 + k] * Wo[k * 128 + c];
            sbig[p] = acc;
        }
        __syncthreads();
        if (tid < HLENN) {
            float m = 0.f;
            for (int k = 0; k < 128; ++k) m += sbig[tid * 128 + k];
            m *= (1.f / 128.f);
            float v = 0.f;
            for (int k = 0; k < 128; ++k) { float dx = sbig[tid * 128 + k] - m; v += dx * dx; }
            smean[tid] = m; svar[tid] = v * (1.f / 128.f);
        }
        __syncthreads();
        for (int p = tid; p < HLENN * 128; p += 512) {
            int t = p >> 7, c = p & 127;
            sxseq[t][c] = (sbig[p] - smean[t]) * rsqrtf(svar[t] + 1e-5f) * ln1[c] + ln1[128 + c];
        }
        __syncthreads();
        // ff1: sbig[0..25600) = relu(xseq @ W1 + b1)
        for (int p = tid; p < HLENN * 512; p += 512) {
            int t = p >> 9, j = p & 511;
            float acc = b1[j];
            #pragma unroll 8
            for (int k = 0; k < 128; ++k) acc += sxseq[t][k] * W1[k * 512 + j];
            sbig[p] = fmaxf(acc, 0.f);
        }
        __syncthreads();
        // ff2 + residual via statically-indexed register staging
        float r2[13];
        #pragma unroll
        for (int i = 0; i < 13; ++i) {
            int p = tid + i * 512;
            if (p < HLENN * 128) {
                int t = p >> 7, c = p & 127;
                float acc = b2[c] + sxseq[t][c];
                #pragma unroll 8
                for (int k = 0; k < 512; ++k) acc += sbig[t * 512 + k] * W2[k * 128 + c];
                r2[i] = acc;
            }
        }
        __syncthreads();
        #pragma unroll
        for (int i = 0; i < 13; ++i) {
            int p = tid + i * 512;
            if (p < HLENN * 128) sbig[p] = r2[i];
        }
        __syncthreads();
        if (tid < HLENN) {
            float m = 0.f;
            for (int k = 0; k < 128; ++k) m += sbig[tid * 128 + k];
            m *= (1.f / 128.f);
            float v = 0.f;
            for (int k = 0; k < 128; ++k) { float dx = sbig[tid * 128 + k] - m; v += dx * dx; }
            smean[tid] = m; svar[tid] = v * (1.f / 128.f);
        }
        __syncthreads();
        for (int p = tid; p < HLENN * 128; p += 512) {
            int t = p >> 7, c = p & 127;
            sxseq[t][c] = (sbig[p] - smean[t]) * rsqrtf(svar[t] + 1e-5f) * ln2[c] + ln2[128 + c];
        }
        __syncthreads();
    }
    // ---- sequence mean ----
    if (tid < 128) {
        float s = 0.f;
        for (int t = 0; t < HLENN; ++t) s += sxseq[t][tid];
        flab[b * 128 + tid] = s * (1.f / HLENN);
    }
}

// ---------------------------------------------------------------------------
__global__ __launch_bounds__(192) void score_kernel(
        const float* __restrict__ feature, const float* __restrict__ flabel,
        const int* __restrict__ t_index,
        const float* __restrict__ W1, const float* __restrict__ b1,
        const float* __restrict__ W2, const float* __restrict__ b2,
        float* __restrict__ score) {
    int b = blockIdx.x / KK, k = blockIdx.x % KK;
    __shared__ float sf[192];
    __shared__ float sred[192];
    int j = threadIdx.x;
    int t = t_index[b * KK + k];
    sf[j] = (j < 64) ? feature[(size_t)t * 64 + j] : flabel[b * 128 + (j - 64)];
    __syncthreads();
    float acc = b1[j];
    #pragma unroll 8
    for (int i = 0; i < 192; ++i) acc += sf[i] * W1[i * 192 + j];
    float h = fmaxf(acc, 0.f);
    sred[j] = h * W2[j];
    __syncthreads();
    if (j < 64) sred[j] += sred[j + 64] + sred[j + 128];
    __syncthreads();
    for (int off = 32; off > 0; off >>= 1) { if (j < off) sred[j] += sred[j + off]; __syncthreads(); }
    if (j == 0) score[b * KK + k] = sred[0] + b2[0];
}

// ---------------------------------------------------------------------------
extern "C" void kernel_launch(void* const* d_in, const int* in_sizes, int n_in,
                              void* d_out, int out_size, void* d_ws, size_t ws_size,
                              hipStream_t stream) {
    const float* poi_emb   = (const float*)d_in[0];
    const float* query_emb = (const float*)d_in[1];
    const float* gate_W    = (const float*)d_in[2];
    const float* gate_b    = (const float*)d_in[3];
    const float* gnn_rel   = (const float*)d_in[4];   // [2,24,64]
    const float* gnn_W     = (const float*)d_in[5];   // [2,128,64]
    const float* gnn_b     = (const float*)d_in[6];   // [2,64]
    const float* g_time_emb= (const float*)d_in[7];
    const float* g_lin_W   = (const float*)d_in[8];
    const float* g_lin_b   = (const float*)d_in[9];
    const float* tf_Wqkv   = (const float*)d_in[10];
    const float* tf_Wo     = (const float*)d_in[11];
    const float* tf_ln1    = (const float*)d_in[12];
    const float* tf_ln2    = (const float*)d_in[13];
    const float* tf_W1     = (const float*)d_in[14];
    const float* tf_b1     = (const float*)d_in[15];
    const float* tf_W2     = (const float*)d_in[16];
    const float* tf_b2     = (const float*)d_in[17];
    const float* mlp_W1    = (const float*)d_in[18];
    const float* mlp_b1    = (const float*)d_in[19];
    const float* mlp_W2    = (const float*)d_in[20];
    const float* mlp_b2    = (const float*)d_in[21];
    const float* hte       = (const float*)d_in[22];
    const int* edge_src    = (const int*)d_in[23];
    const int* edge_dst    = (const int*)d_in[24];
    const int* edge_type   = (const int*)d_in[25];
    const int* r_index     = (const int*)d_in[27];    // h_index (26) unused
    const int* t_index     = (const int*)d_in[28];
    const int* history_poi = (const int*)d_in[29];
    const int* g_time      = (const int*)d_in[30];

    float* ws = (float*)d_ws;
    float* xA    = ws;                     // 20000*64
    float* initb = xA    + 1280000;        // 20000*64
    float* y     = initb + 1280000;        // 20032*64
    float* z     = y     + 1282048;
    float* y2    = z     + 1282048;
    float* z2    = y2    + 1282048;
    float* flab  = z2    + 1282048;        // 1024
    int* rowptr  = (int*)(flab + 1024);    // 3*(NN+1)
    int* colp    = rowptr + 3 * (NN + 1);  // 3*EE
    int* deg     = colp + 3 * EE;          // 3*NN

    // CSR + degree for all snapshots (one launch)
    csr_kernel<<<3, 1024, 0, stream>>>(edge_src, edge_dst, edge_type,
                                       rowptr, colp, deg);

    // GNN: 3 launches per snapshot
    for (int s = 0; s < SS; ++s) {
        const int* rp = rowptr + s * (NN + 1);
        const int* cp = colp + s * EE;
        initgemm_kernel<<<313, 256, 0, stream>>>(
            poi_emb, deg + s * NN, gate_W, gate_b, xA,
            gnn_rel,                // layer-0 rel rows
            gnn_W,                  // layer-0 [128][64]
            initb, y, z, s > 0 ? 1 : 0);
        fingemm_kernel<<<313, 256, 0, stream>>>(
            y, z, rp, cp, gnn_b,
            gnn_rel + 24 * 64,      // layer-1 rel rows
            gnn_W + 128 * 64,       // layer-1 [128][64]
            initb, y2, z2);
        fin_kernel<<<NN / 16, 256, 0, stream>>>(y2, z2, rp, cp, gnn_b + 64, xA);
    }

    // query + history gather + transformer + mean (one launch)
    tf_kernel<<<BB, 512, 0, stream>>>(
        xA, query_emb, r_index, g_time_emb, g_time, g_lin_W, g_lin_b,
        history_poi, hte, tf_Wqkv, tf_Wo, tf_ln1, tf_ln2,
        tf_W1, tf_b1, tf_W2, tf_b2, flab);

    // scoring
    score_kernel<<<BB * KK, 192, 0, stream>>>(xA, flab, t_index,
                                              mlp_W1, mlp_b1, mlp_W2, mlp_b2,
                                              (float*)d_out);
}

// Round 8
// 713.389 us; speedup vs baseline: 2.0490x; 2.0490x over previous
//
#include <hip/hip_runtime.h>
#include <hip/hip_bf16.h>
#include <math.h>

#define DD   64
#define DD2  128
#define NN   20000
#define RR   24
#define SS   3
#define EE   60000
#define BB   8
#define KK   101
#define HLENN 50
#define MROWS 20024   // 20000 nodes + 24 appended rel rows

// ---------------------------------------------------------------------------
// Full CSR build + degree for all 3 snapshots. 3 blocks (one per snapshot),
// 1024 threads, 80KB LDS histogram.
__global__ __launch_bounds__(1024) void csr_kernel(
        const int* __restrict__ src, const int* __restrict__ dst,
        const int* __restrict__ et,
        int* __restrict__ rowptr,   // [3][NN+1]
        int* __restrict__ colp,     // [3][EE]  src | et<<16, grouped by dst
        int* __restrict__ deg) {    // [3][NN]  in+out degree
    __shared__ int lh[NN];
    __shared__ int sp[1024];
    int s = blockIdx.x, t = threadIdx.x;
    const int* ps = src + s * EE;
    const int* pd = dst + s * EE;
    const int* pt = et + s * EE;
    int* rp = rowptr + s * (NN + 1);
    for (int i = t; i < NN; i += 1024) lh[i] = 0;
    __syncthreads();
    for (int e = t; e < EE; e += 1024) atomicAdd(&lh[pd[e]], 1);
    __syncthreads();
    int base = t * 20, sum = 0;
    for (int i = 0; i < 20; ++i) { int idx = base + i; if (idx < NN) sum += lh[idx]; }
    sp[t] = sum;
    __syncthreads();
    for (int off = 1; off < 1024; off <<= 1) {
        int v = (t >= off) ? sp[t - off] : 0;
        __syncthreads();
        sp[t] += v;
        __syncthreads();
    }
    int run = sp[t] - sum;
    for (int i = 0; i < 20; ++i) {
        int idx = base + i;
        if (idx < NN) { rp[idx] = run; int c = lh[idx]; lh[idx] = run; run += c; }
    }
    if (t == 1023) rp[NN] = sp[1023];
    __syncthreads();
    for (int e = t; e < EE; e += 1024) {
        int pos = atomicAdd(&lh[pd[e]], 1);
        colp[s * EE + pos] = ps[e] | (pt[e] << 16);
    }
    __syncthreads();
    for (int i = t; i < NN; i += 1024) lh[i] = 0;
    __syncthreads();
    for (int e = t; e < EE; e += 1024) atomicAdd(&lh[ps[e]], 1);
    __syncthreads();
    for (int i = t; i < NN; i += 1024)
        deg[s * NN + i] = lh[i] + (rp[i + 1] - rp[i]);
}

// ---------------------------------------------------------------------------
// Stage 1: init (deg*poi, gated for s>0) fused with layer-0 GEMM pair.
__global__ __launch_bounds__(256) void initgemm_kernel(
        const float* __restrict__ poi, const int* __restrict__ deg,
        const float* __restrict__ gate_W, const float* __restrict__ gate_b,
        const float* __restrict__ xprev, const float* __restrict__ rel,
        const float* __restrict__ W,   // [128][64]: rows 0..63 Wt, 64..127 Wb
        float* __restrict__ initb, float* __restrict__ y, float* __restrict__ z,
        int use_gate) {
    __shared__ float sGW[64][64];
    __shared__ float sA[64][68];
    __shared__ float sBt[64][68];
    __shared__ float sBb[64][68];
    __shared__ float srow[4][64];
    int tid = threadIdx.x;
    int li = tid >> 6, d = tid & 63;
    int row0 = blockIdx.x * 64;
    if (use_gate) {
        for (int i = tid; i < 64 * 64; i += 256) sGW[i >> 6][i & 63] = gate_W[i];
        __syncthreads();
    }
    float gb = use_gate ? gate_b[d] : 0.f;
    for (int it = 0; it < 16; ++it) {
        int rl = it * 4 + li;
        int row = row0 + rl;
        float iv;
        if (row < NN)           iv = (float)deg[row] * poi[(size_t)row * 64 + d];
        else if (row < MROWS)   iv = rel[(row - NN) * 64 + d];
        else                    iv = 0.f;
        if (use_gate) {
            float ov = (row < NN) ? xprev[(size_t)row * 64 + d] : 0.f;
            srow[li][d] = ov;
            __syncthreads();
            float acc = gb;
            #pragma unroll
            for (int k = 0; k < 64; ++k) acc += srow[li][k] * sGW[k][d];
            float g = 1.f / (1.f + expf(-acc));
            if (row < NN) iv = iv * g + (1.f - g) * ov;
            __syncthreads();
        }
        sA[rl][d] = iv;
        if (row < NN) initb[(size_t)row * 64 + d] = iv;
    }
    for (int i = tid; i < 64 * 64; i += 256) {
        sBt[i >> 6][i & 63] = W[i];
        sBb[i >> 6][i & 63] = W[64 * 64 + i];
    }
    __syncthreads();
    int tr = tid >> 4, tc = tid & 15;
    float accY[4][4] = {{0.f}}, accZ[4][4] = {{0.f}};
    #pragma unroll 16
    for (int k = 0; k < 64; ++k) {
        float4 bt = *(const float4*)&sBt[k][tc * 4];
        float4 bz = *(const float4*)&sBb[k][tc * 4];
        #pragma unroll
        for (int i = 0; i < 4; ++i) {
            float a = sA[tr * 4 + i][k];
            accY[i][0] += a * bt.x; accY[i][1] += a * bt.y; accY[i][2] += a * bt.z; accY[i][3] += a * bt.w;
            accZ[i][0] += a * bz.x; accZ[i][1] += a * bz.y; accZ[i][2] += a * bz.z; accZ[i][3] += a * bz.w;
        }
    }
    #pragma unroll
    for (int i = 0; i < 4; ++i) {
        int row = row0 + tr * 4 + i;
        if (row < MROWS) {
            *(float4*)(y + (size_t)row * 64 + tc * 4) = make_float4(accY[i][0], accY[i][1], accY[i][2], accY[i][3]);
            *(float4*)(z + (size_t)row * 64 + tc * 4) = make_float4(accZ[i][0], accZ[i][1], accZ[i][2], accZ[i][3]);
        }
    }
}

// ---------------------------------------------------------------------------
// Stage 2: fin of layer 0 fused with layer-1 GEMM pair.
__global__ __launch_bounds__(256) void fingemm_kernel(
        const float* __restrict__ y, const float* __restrict__ z,
        const int* __restrict__ rp, const int* __restrict__ cp,
        const float* __restrict__ bias0, const float* __restrict__ rel1,
        const float* __restrict__ W1,  // layer-1 [128][64]
        const float* __restrict__ initb,
        float* __restrict__ y2, float* __restrict__ z2) {
    __shared__ float srelW[24][64];
    __shared__ float sA[64][68];
    __shared__ float sAi[64][68];
    __shared__ float sBt[64][68];
    __shared__ float sBb[64][68];
    int tid = threadIdx.x;
    int li = tid >> 6, d = tid & 63;
    int row0 = blockIdx.x * 64;
    for (int i = tid; i < 24 * 64; i += 256) srelW[i >> 6][i & 63] = y[(size_t)NN * 64 + i];
    for (int i = tid; i < 64 * 64; i += 256) {
        sBt[i >> 6][i & 63] = W1[i];
        sBb[i >> 6][i & 63] = W1[64 * 64 + i];
    }
    for (int i = tid; i < 64 * 16; i += 256) {
        int r = i >> 4, cq = i & 15;
        int row = row0 + r;
        float4 v = make_float4(0.f, 0.f, 0.f, 0.f);
        if (row < NN) v = *(const float4*)(initb + (size_t)row * 64 + cq * 4);
        *(float4*)&sAi[r][cq * 4] = v;
    }
    __syncthreads();
    float bb0 = bias0[d];
    for (int it = 0; it < 16; ++it) {
        int rl = it * 4 + li;
        int row = row0 + rl;
        float val = 0.f;
        if (row < NN) {
            float acc = z[(size_t)row * 64 + d] + bb0;
            int e0 = rp[row], e1 = rp[row + 1];
            for (int e = e0; e < e1; ++e) {
                int pack = cp[e];
                acc += y[(size_t)(pack & 0xFFFF) * 64 + d] + srelW[pack >> 16][d];
            }
            val = fmaxf(acc, 0.f);
        } else if (row < MROWS) {
            val = rel1[(row - NN) * 64 + d];
        }
        sA[rl][d] = val;
    }
    __syncthreads();
    int tr = tid >> 4, tc = tid & 15;
    float accY[4][4] = {{0.f}}, accZ[4][4] = {{0.f}};
    #pragma unroll 16
    for (int k = 0; k < 64; ++k) {
        float4 bt = *(const float4*)&sBt[k][tc * 4];
        float4 bz = *(const float4*)&sBb[k][tc * 4];
        #pragma unroll
        for (int i = 0; i < 4; ++i) {
            float a  = sA[tr * 4 + i][k];
            float ai = sAi[tr * 4 + i][k];
            accY[i][0] += a * bt.x;  accY[i][1] += a * bt.y;  accY[i][2] += a * bt.z;  accY[i][3] += a * bt.w;
            accZ[i][0] += ai * bz.x; accZ[i][1] += ai * bz.y; accZ[i][2] += ai * bz.z; accZ[i][3] += ai * bz.w;
        }
    }
    #pragma unroll
    for (int i = 0; i < 4; ++i) {
        int row = row0 + tr * 4 + i;
        if (row < MROWS) {
            *(float4*)(y2 + (size_t)row * 64 + tc * 4) = make_float4(accY[i][0], accY[i][1], accY[i][2], accY[i][3]);
            *(float4*)(z2 + (size_t)row * 64 + tc * 4) = make_float4(accZ[i][0], accZ[i][1], accZ[i][2], accZ[i][3]);
        }
    }
}

// ---------------------------------------------------------------------------
// Stage 3: final fin of layer 1 -> snapshot output x (xA).
__global__ __launch_bounds__(256) void fin_kernel(
        const float* __restrict__ y, const float* __restrict__ z,
        const int* __restrict__ rowptr, const int* __restrict__ colp,
        const float* __restrict__ bias, float* __restrict__ xout) {
    __shared__ float srelW[24][64];
    int tid = threadIdx.x;
    for (int i = tid; i < 24 * 64; i += 256) srelW[i >> 6][i & 63] = y[(size_t)NN * 64 + i];
    int d = tid & 63, w = tid >> 6;
    float bb = bias[d];
    __syncthreads();
    int base = blockIdx.x * 16 + w * 4;
    for (int n = 0; n < 4; ++n) {
        int node = base + n;
        float acc = z[(size_t)node * 64 + d] + bb;
        int e0 = rowptr[node], e1 = rowptr[node + 1];
        for (int e = e0; e < e1; ++e) {
            int pack = colp[e];
            acc += y[(size_t)(pack & 0xFFFF) * 64 + d] + srelW[pack >> 16][d];
        }
        xout[(size_t)node * 64 + d] = fmaxf(acc, 0.f);
    }
}

// ---------------------------------------------------------------------------
// query[b] = query_emb[r_index[b]] through 3x ((q + time) @ g_lin_W + b)
__global__ void query_kernel(const float* __restrict__ query_emb, const int* __restrict__ r_index,
                             const float* __restrict__ g_time_emb, const int* __restrict__ g_time,
                             const float* __restrict__ g_lin_W, const float* __restrict__ g_lin_b,
                             float* __restrict__ query) {
    __shared__ float sW[64][64];
    __shared__ float sq[8][64];
    int b = threadIdx.x >> 6;
    int d = threadIdx.x & 63;
    for (int i = threadIdx.x; i < 64 * 64; i += 512) sW[i >> 6][i & 63] = g_lin_W[i];
    float q = query_emb[r_index[b] * 64 + d];
    for (int s = 0; s < SS; ++s) {
        float t = q + g_time_emb[g_time[s] * 64 + d];
        sq[b][d] = t;
        __syncthreads();
        float acc = g_lin_b[d];
        #pragma unroll
        for (int k = 0; k < 64; ++k) acc += sq[b][k] * sW[k][d];
        q = acc;
        __syncthreads();
    }
    query[b * 64 + d] = q;
}

__global__ void xseq_kernel(const float* __restrict__ feature, const float* __restrict__ query,
                            const int* __restrict__ history_poi, const float* __restrict__ hte,
                            float* __restrict__ xseq) {
    int idx = blockIdx.x * 256 + threadIdx.x;
    if (idx >= BB * HLENN * DD2) return;
    int c = idx & 127;
    int bt = idx >> 7;
    int b = bt / HLENN, t = bt % HLENN;
    float v = (c < 64) ? feature[(size_t)history_poi[b * HLENN + t] * 64 + c]
                       : query[b * 64 + (c - 64)];
    xseq[idx] = v + hte[idx];
}

// qkv for 4 rows per block; 384 threads (thread = output col)
__global__ void qkv4_kernel(const float* __restrict__ xseq, const float* __restrict__ Wqkv,
                            float* __restrict__ qkvb) {
    __shared__ float sx[4][128];
    int tid = threadIdx.x;
    int row0 = blockIdx.x * 4;
    for (int i = tid; i < 512; i += 384) sx[i >> 7][i & 127] = xseq[row0 * 128 + i];
    __syncthreads();
    float a0 = 0.f, a1 = 0.f, a2 = 0.f, a3 = 0.f;
    #pragma unroll 8
    for (int k = 0; k < 128; ++k) {
        float w = Wqkv[k * 384 + tid];
        a0 += sx[0][k] * w; a1 += sx[1][k] * w; a2 += sx[2][k] * w; a3 += sx[3][k] * w;
    }
    qkvb[(row0 + 0) * 384 + tid] = a0;
    qkvb[(row0 + 1) * 384 + tid] = a1;
    qkvb[(row0 + 2) * 384 + tid] = a2;
    qkvb[(row0 + 3) * 384 + tid] = a3;
}

// attention per (b, head): 16 blocks, 256 threads
__global__ void attn_kernel(const float* __restrict__ qkv, float* __restrict__ attnout) {
    int b = blockIdx.x >> 1, h = blockIdx.x & 1;
    __shared__ float sq[HLENN][64], sk[HLENN][64], sv[HLENN][64];
    __shared__ float ss[HLENN][HLENN];
    for (int i = threadIdx.x; i < HLENN * 64; i += 256) {
        int t = i >> 6, d = i & 63;
        const float* base = qkv + (size_t)(b * HLENN + t) * 384 + h * 64 + d;
        sq[t][d] = base[0];
        sk[t][d] = base[128];
        sv[t][d] = base[256];
    }
    __syncthreads();
    for (int p = threadIdx.x; p < HLENN * HLENN; p += 256) {
        int i = p / HLENN, j = p % HLENN;
        float acc = 0.f;
        #pragma unroll 8
        for (int d = 0; d < 64; ++d) acc += sq[i][d] * sk[j][d];
        ss[i][j] = acc * 0.125f;
    }
    __syncthreads();
    if (threadIdx.x < HLENN) {
        int i = threadIdx.x;
        float m = -1e30f;
        for (int j = 0; j < HLENN; ++j) m = fmaxf(m, ss[i][j]);
        float sum = 0.f;
        for (int j = 0; j < HLENN; ++j) { float e = expf(ss[i][j] - m); ss[i][j] = e; sum += e; }
        float inv = 1.f / sum;
        for (int j = 0; j < HLENN; ++j) ss[i][j] *= inv;
    }
    __syncthreads();
    for (int p = threadIdx.x; p < HLENN * 64; p += 256) {
        int i = p >> 6, d = p & 63;
        float acc = 0.f;
        for (int j = 0; j < HLENN; ++j) acc += ss[i][j] * sv[j][d];
        attnout[(size_t)(b * HLENN + i) * 128 + h * 64 + d] = acc;
    }
}

// out = LN(resid + aout @ Wo), 4 rows/block, 512 threads
__global__ void addLN4_kernel(const float* __restrict__ aout, const float* __restrict__ Wo,
                              const float* __restrict__ ln, float* __restrict__ xseq) {
    __shared__ float sa[4][128];
    __shared__ float sred[4][128];
    int tid = threadIdx.x;
    int r = tid >> 7, c = tid & 127;
    int row0 = blockIdx.x * 4;
    sa[r][c] = aout[(row0 + r) * 128 + c];
    __syncthreads();
    float acc = xseq[(row0 + r) * 128 + c];
    #pragma unroll 8
    for (int k = 0; k < 128; ++k) acc += sa[r][k] * Wo[k * 128 + c];
    sred[r][c] = acc; __syncthreads();
    for (int off = 64; off > 0; off >>= 1) { if (c < off) sred[r][c] += sred[r][c + off]; __syncthreads(); }
    float mean = sred[r][0] * (1.f / 128.f);
    __syncthreads();
    float dx = acc - mean;
    sred[r][c] = dx * dx; __syncthreads();
    for (int off = 64; off > 0; off >>= 1) { if (c < off) sred[r][c] += sred[r][c + off]; __syncthreads(); }
    float var = sred[r][0] * (1.f / 128.f);
    xseq[(row0 + r) * 128 + c] = dx * rsqrtf(var + 1e-5f) * ln[c] + ln[128 + c];
}

// fused ff1 + relu + ff2 + residual + LN, 4 rows/block, 512 threads
__global__ void ffLN4_kernel(const float* __restrict__ xin, const float* __restrict__ W1,
                             const float* __restrict__ b1, const float* __restrict__ W2,
                             const float* __restrict__ b2, const float* __restrict__ ln,
                             float* __restrict__ xout) {
    __shared__ float sx[4][128];
    __shared__ float sh[4][512];
    __shared__ float spart[4][4][128];
    __shared__ float sred[4][128];
    int tid = threadIdx.x;
    int row0 = blockIdx.x * 4;
    { int r = tid >> 7, c = tid & 127; sx[r][c] = xin[(row0 + r) * 128 + c]; }
    __syncthreads();
    {
        float bb = b1[tid];
        float a0 = bb, a1 = bb, a2 = bb, a3 = bb;
        #pragma unroll 8
        for (int k = 0; k < 128; ++k) {
            float w = W1[k * 512 + tid];
            a0 += sx[0][k] * w; a1 += sx[1][k] * w; a2 += sx[2][k] * w; a3 += sx[3][k] * w;
        }
        sh[0][tid] = fmaxf(a0, 0.f); sh[1][tid] = fmaxf(a1, 0.f);
        sh[2][tid] = fmaxf(a2, 0.f); sh[3][tid] = fmaxf(a3, 0.f);
    }
    __syncthreads();
    int kc = tid >> 7, c = tid & 127;
    float p0 = 0.f, p1 = 0.f, p2 = 0.f, p3 = 0.f;
    #pragma unroll 8
    for (int kk = 0; kk < 128; ++kk) {
        int k = kc * 128 + kk;
        float w = W2[k * 128 + c];
        p0 += sh[0][k] * w; p1 += sh[1][k] * w; p2 += sh[2][k] * w; p3 += sh[3][k] * w;
    }
    spart[kc][0][c] = p0; spart[kc][1][c] = p1; spart[kc][2][c] = p2; spart[kc][3][c] = p3;
    __syncthreads();
    int r = kc;
    float acc = b2[c] + spart[0][r][c] + spart[1][r][c] + spart[2][r][c] + spart[3][r][c] + sx[r][c];
    sred[r][c] = acc; __syncthreads();
    for (int off = 64; off > 0; off >>= 1) { if (c < off) sred[r][c] += sred[r][c + off]; __syncthreads(); }
    float mean = sred[r][0] * (1.f / 128.f);
    __syncthreads();
    float dx = acc - mean;
    sred[r][c] = dx * dx; __syncthreads();
    for (int off = 64; off > 0; off >>= 1) { if (c < off) sred[r][c] += sred[r][c + off]; __syncthreads(); }
    float var = sred[r][0] * (1.f / 128.f);
    xout[(row0 + r) * 128 + c] = dx * rsqrtf(var + 1e-5f) * ln[c] + ln[128 + c];
}

__global__ void mean_kernel(const float* __restrict__ xseq, float* __restrict__ flabel) {
    int i = blockIdx.x * 256 + threadIdx.x;
    if (i >= BB * 128) return;
    int b = i >> 7, c = i & 127;
    float s = 0.f;
    for (int t = 0; t < HLENN; ++t) s += xseq[(b * HLENN + t) * 128 + c];
    flabel[i] = s * (1.f / HLENN);
}

__global__ __launch_bounds__(192) void score_kernel(
        const float* __restrict__ feature, const float* __restrict__ flabel,
        const int* __restrict__ t_index,
        const float* __restrict__ W1, const float* __restrict__ b1,
        const float* __restrict__ W2, const float* __restrict__ b2,
        float* __restrict__ score) {
    int b = blockIdx.x / KK, k = blockIdx.x % KK;
    __shared__ float sf[192];
    __shared__ float sred[192];
    int j = threadIdx.x;
    int t = t_index[b * KK + k];
    sf[j] = (j < 64) ? feature[(size_t)t * 64 + j] : flabel[b * 128 + (j - 64)];
    __syncthreads();
    float acc = b1[j];
    #pragma unroll 8
    for (int i = 0; i < 192; ++i) acc += sf[i] * W1[i * 192 + j];
    float h = fmaxf(acc, 0.f);
    sred[j] = h * W2[j];
    __syncthreads();
    if (j < 64) sred[j] += sred[j + 64] + sred[j + 128];
    __syncthreads();
    for (int off = 32; off > 0; off >>= 1) { if (j < off) sred[j] += sred[j + off]; __syncthreads(); }
    if (j == 0) score[b * KK + k] = sred[0] + b2[0];
}

// ---------------------------------------------------------------------------
extern "C" void kernel_launch(void* const* d_in, const int* in_sizes, int n_in,
                              void* d_out, int out_size, void* d_ws, size_t ws_size,
                              hipStream_t stream) {
    const float* poi_emb   = (const float*)d_in[0];
    const float* query_emb = (const float*)d_in[1];
    const float* gate_W    = (const float*)d_in[2];
    const float* gate_b    = (const float*)d_in[3];
    const float* gnn_rel   = (const float*)d_in[4];   // [2,24,64]
    const float* gnn_W     = (const float*)d_in[5];   // [2,128,64]
    const float* gnn_b     = (const float*)d_in[6];   // [2,64]
    const float* g_time_emb= (const float*)d_in[7];
    const float* g_lin_W   = (const float*)d_in[8];
    const float* g_lin_b   = (const float*)d_in[9];
    const float* tf_Wqkv   = (const float*)d_in[10];
    const float* tf_Wo     = (const float*)d_in[11];
    const float* tf_ln1    = (const float*)d_in[12];
    const float* tf_ln2    = (const float*)d_in[13];
    const float* tf_W1     = (const float*)d_in[14];
    const float* tf_b1     = (const float*)d_in[15];
    const float* tf_W2     = (const float*)d_in[16];
    const float* tf_b2     = (const float*)d_in[17];
    const float* mlp_W1    = (const float*)d_in[18];
    const float* mlp_b1    = (const float*)d_in[19];
    const float* mlp_W2    = (const float*)d_in[20];
    const float* mlp_b2    = (const float*)d_in[21];
    const float* hte       = (const float*)d_in[22];
    const int* edge_src    = (const int*)d_in[23];
    const int* edge_dst    = (const int*)d_in[24];
    const int* edge_type   = (const int*)d_in[25];
    const int* r_index     = (const int*)d_in[27];    // h_index (26) unused
    const int* t_index     = (const int*)d_in[28];
    const int* history_poi = (const int*)d_in[29];
    const int* g_time      = (const int*)d_in[30];

    float* ws = (float*)d_ws;
    float* xA    = ws;                     // 20000*64
    float* initb = xA    + 1280000;
    float* y     = initb + 1280000;        // 20032*64
    float* z     = y     + 1282048;
    float* y2    = z     + 1282048;
    float* z2    = y2    + 1282048;
    float* query = z2    + 1282048;        // 512
    float* xseq  = query + 512;            // 51200
    float* qkvb  = xseq  + 51200;          // 153600
    float* aout  = qkvb  + 153600;         // 51200
    float* flab  = aout  + 51200;          // 1024
    int* rowptr  = (int*)(flab + 1024);    // 3*(NN+1)
    int* colp    = rowptr + 3 * (NN + 1);  // 3*EE
    int* deg     = colp + 3 * EE;          // 3*NN

    // CSR + degree for all snapshots (one launch)
    csr_kernel<<<3, 1024, 0, stream>>>(edge_src, edge_dst, edge_type,
                                       rowptr, colp, deg);

    // GNN: 3 launches per snapshot
    for (int s = 0; s < SS; ++s) {
        const int* rp = rowptr + s * (NN + 1);
        const int* cp = colp + s * EE;
        initgemm_kernel<<<313, 256, 0, stream>>>(
            poi_emb, deg + s * NN, gate_W, gate_b, xA,
            gnn_rel, gnn_W, initb, y, z, s > 0 ? 1 : 0);
        fingemm_kernel<<<313, 256, 0, stream>>>(
            y, z, rp, cp, gnn_b,
            gnn_rel + 24 * 64, gnn_W + 128 * 64, initb, y2, z2);
        fin_kernel<<<NN / 16, 256, 0, stream>>>(y2, z2, rp, cp, gnn_b + 64, xA);
    }

    // ---- query path ----
    query_kernel<<<1, 512, 0, stream>>>(query_emb, r_index, g_time_emb, g_time,
                                        g_lin_W, g_lin_b, query);
    xseq_kernel<<<(BB * HLENN * 128 + 255) / 256, 256, 0, stream>>>(xA, query, history_poi, hte, xseq);

    // ---- transformer (2 layers on [8,50,128]) — split kernels, 100-block grids ----
    for (int l = 0; l < 2; ++l) {
        qkv4_kernel<<<BB * HLENN / 4, 384, 0, stream>>>(xseq, tf_Wqkv + l * 128 * 384, qkvb);
        attn_kernel<<<BB * 2, 256, 0, stream>>>(qkvb, aout);
        addLN4_kernel<<<BB * HLENN / 4, 512, 0, stream>>>(aout, tf_Wo + l * 128 * 128,
                                                          tf_ln1 + l * 256, xseq);
        ffLN4_kernel<<<BB * HLENN / 4, 512, 0, stream>>>(xseq, tf_W1 + l * 128 * 512,
                                                         tf_b1 + l * 512, tf_W2 + l * 512 * 128,
                                                         tf_b2 + l * 128, tf_ln2 + l * 256, xseq);
    }

    // ---- scoring ----
    mean_kernel<<<(BB * 128 + 255) / 256, 256, 0, stream>>>(xseq, flab);
    score_kernel<<<BB * KK, 192, 0, stream>>>(xA, flab, t_index,
                                              mlp_W1, mlp_b1, mlp_W2, mlp_b2, (float*)d_out);
}

// Round 10
// 533.485 us; speedup vs baseline: 2.7400x; 1.3372x over previous
//
#include <hip/hip_runtime.h>
#include <hip/hip_bf16.h>
#include <math.h>

#define DD   64
#define DD2  128
#define NN   20000
#define RR   24
#define SS   3
#define EE   60000
#define BB   8
#define KK   101
#define HLENN 50
#define MROWS 20024   // 20000 nodes + 24 appended rel rows

// ---------------------------------------------------------------------------
// histogram by dst (for CSR) + full degree (src+dst counts). Wide: (235,3).
__global__ void hist_kernel(const int* __restrict__ src, const int* __restrict__ dst,
                            int* __restrict__ hist, int* __restrict__ deg) {
    int s = blockIdx.y;
    int e = blockIdx.x * 256 + threadIdx.x;
    if (e < EE) {
        int d0 = dst[s * EE + e], s0 = src[s * EE + e];
        atomicAdd(&hist[s * NN + d0], 1);
        atomicAdd(&deg[s * NN + d0], 1);
        atomicAdd(&deg[s * NN + s0], 1);
    }
}

// exclusive scan of hist -> rowptr (N+1) and cursor copy. One block per snapshot.
__global__ void scan_kernel(const int* __restrict__ hist, int* __restrict__ rowptr,
                            int* __restrict__ cursor) {
    int s = blockIdx.x, t = threadIdx.x;
    const int* h = hist + s * NN;
    int* rp = rowptr + s * (NN + 1);
    int* cur = cursor + s * NN;
    __shared__ int sp[1024];
    int base = t * 20, sum = 0;
    for (int i = 0; i < 20; ++i) { int idx = base + i; if (idx < NN) sum += h[idx]; }
    sp[t] = sum;
    __syncthreads();
    for (int off = 1; off < 1024; off <<= 1) {
        int v = (t >= off) ? sp[t - off] : 0;
        __syncthreads();
        sp[t] += v;
        __syncthreads();
    }
    int run = sp[t] - sum;  // exclusive
    for (int i = 0; i < 20; ++i) {
        int idx = base + i;
        if (idx < NN) { rp[idx] = run; cur[idx] = run; run += h[idx]; }
    }
    if (t == 1023) rp[NN] = sp[1023];
}

// place edges into CSR slots: col[pos] = src | (et<<16). Wide: (235,3).
__global__ void place_kernel(const int* __restrict__ src, const int* __restrict__ dst,
                             const int* __restrict__ et, int* __restrict__ cursor,
                             int* __restrict__ colp) {
    int s = blockIdx.y;
    int e = blockIdx.x * 256 + threadIdx.x;
    if (e < EE) {
        int d0 = dst[s * EE + e];
        int pos = atomicAdd(&cursor[s * NN + d0], 1);
        colp[s * EE + pos] = src[s * EE + e] | (et[s * EE + e] << 16);
    }
}

// init[n,d] = deg[n]*poi[n,d], gated against previous output for s>0. 5000 blocks.
__global__ void init_kernel(const float* __restrict__ poi, const int* __restrict__ deg,
                            const float* __restrict__ gate_W, const float* __restrict__ gate_b,
                            const float* __restrict__ xprev, float* __restrict__ initb,
                            int use_gate) {
    __shared__ float sW[64][64];
    __shared__ float srow[4][64];
    int li = threadIdx.x >> 6, d = threadIdx.x & 63;
    int node = blockIdx.x * 4 + li;   // 5000 blocks * 4 = 20000 exact
    if (use_gate) {
        for (int i = threadIdx.x; i < 64 * 64; i += 256) sW[i >> 6][i & 63] = gate_W[i];
    }
    float iv = (float)deg[node] * poi[(size_t)node * 64 + d];
    if (use_gate) {
        float ov = xprev[(size_t)node * 64 + d];
        srow[li][d] = ov;
        __syncthreads();
        float acc = gate_b[d];
        #pragma unroll
        for (int k = 0; k < 64; ++k) acc += srow[li][k] * sW[k][d];
        float g = 1.f / (1.f + expf(-acc));
        iv = iv * g + (1.f - g) * ov;
    }
    initb[(size_t)node * 64 + d] = iv;
}

// batched C = A @ B, A: [20024 x 64] (rows >=20000 from Ar), B: [64 x 64].
// 64x64 tile per block, 256 threads, 4x4 micro-tile. Grid (313, 2).
__global__ void gemm64_kernel(const float* __restrict__ A0a, const float* __restrict__ Ar_a,
                              const float* __restrict__ Ba, float* __restrict__ Ca,
                              const float* __restrict__ A0b, const float* __restrict__ Ar_b,
                              const float* __restrict__ Bb, float* __restrict__ Cb) {
    const float* A0 = blockIdx.y ? A0b : A0a;
    const float* Ar = blockIdx.y ? Ar_b : Ar_a;
    const float* B  = blockIdx.y ? Bb  : Ba;
    float* C        = blockIdx.y ? Cb  : Ca;
    __shared__ float sA[64][68];
    __shared__ float sB[64][68];
    int tid = threadIdx.x;
    int row0 = blockIdx.x * 64;
    for (int i = tid; i < 64 * 16; i += 256) {
        int r = i >> 4, cq = i & 15;
        int row = row0 + r;
        float4 v = make_float4(0.f, 0.f, 0.f, 0.f);
        if (row < NN)         v = *(const float4*)(A0 + (size_t)row * 64 + cq * 4);
        else if (row < MROWS) v = *(const float4*)(Ar + (size_t)(row - NN) * 64 + cq * 4);
        *(float4*)&sA[r][cq * 4] = v;
        float4 w = *(const float4*)(B + (size_t)r * 64 + cq * 4);
        *(float4*)&sB[r][cq * 4] = w;
    }
    __syncthreads();
    int tr = tid >> 4, tc = tid & 15;
    float acc[4][4] = {{0.f}};
    #pragma unroll 16
    for (int k = 0; k < 64; ++k) {
        float4 b4 = *(const float4*)&sB[k][tc * 4];
        float a0 = sA[tr * 4 + 0][k];
        float a1 = sA[tr * 4 + 1][k];
        float a2 = sA[tr * 4 + 2][k];
        float a3 = sA[tr * 4 + 3][k];
        acc[0][0] += a0 * b4.x; acc[0][1] += a0 * b4.y; acc[0][2] += a0 * b4.z; acc[0][3] += a0 * b4.w;
        acc[1][0] += a1 * b4.x; acc[1][1] += a1 * b4.y; acc[1][2] += a1 * b4.z; acc[1][3] += a1 * b4.w;
        acc[2][0] += a2 * b4.x; acc[2][1] += a2 * b4.y; acc[2][2] += a2 * b4.z; acc[2][3] += a2 * b4.w;
        acc[3][0] += a3 * b4.x; acc[3][1] += a3 * b4.y; acc[3][2] += a3 * b4.z; acc[3][3] += a3 * b4.w;
    }
    #pragma unroll
    for (int i = 0; i < 4; ++i) {
        int row = row0 + tr * 4 + i;
        if (row < MROWS) {
            *(float4*)(C + (size_t)row * 64 + tc * 4) = make_float4(acc[i][0], acc[i][1], acc[i][2], acc[i][3]);
        }
    }
}

// x_out[n] = relu( z[n] + b + sum_{e in-edges(n)} ( y[src_e] + relW[et_e] ) )
// relW = y rows 20000..20023 (staged in LDS). 1250 blocks.
__global__ void fin_kernel(const float* __restrict__ y, const float* __restrict__ z,
                           const int* __restrict__ rowptr, const int* __restrict__ colp,
                           const float* __restrict__ bias, float* __restrict__ xout) {
    __shared__ float srelW[24][64];
    int tid = threadIdx.x;
    for (int i = tid; i < 24 * 64; i += 256) srelW[i >> 6][i & 63] = y[(size_t)NN * 64 + i];
    int d = tid & 63, w = tid >> 6;
    float bb = bias[d];
    __syncthreads();
    int base = blockIdx.x * 16 + w * 4;   // 1250 blocks * 16 = 20000 exact
    for (int n = 0; n < 4; ++n) {
        int node = base + n;
        float acc = z[(size_t)node * 64 + d] + bb;
        int e0 = rowptr[node], e1 = rowptr[node + 1];
        for (int e = e0; e < e1; ++e) {
            int pack = colp[e];
            acc += y[(size_t)(pack & 0xFFFF) * 64 + d] + srelW[pack >> 16][d];
        }
        xout[(size_t)node * 64 + d] = fmaxf(acc, 0.f);
    }
}

// ---------------------------------------------------------------------------
// Merged query chain + xseq build. 25 blocks x 256 threads; each block
// redundantly computes the 8 query vectors (trivial work) then fills its
// 2048-element slice of xseq.
__global__ void queryxseq_kernel(const float* __restrict__ feature,
                                 const float* __restrict__ query_emb,
                                 const int* __restrict__ r_index,
                                 const float* __restrict__ g_time_emb,
                                 const int* __restrict__ g_time,
                                 const float* __restrict__ g_lin_W,
                                 const float* __restrict__ g_lin_b,
                                 const int* __restrict__ history_poi,
                                 const float* __restrict__ hte,
                                 float* __restrict__ xseq) {
    __shared__ float sW[64][64];
    __shared__ float sq[8][64];
    __shared__ float st[8][64];
    int tid = threadIdx.x;
    int b4 = tid >> 6, d = tid & 63;
    for (int i = tid; i < 64 * 64; i += 256) sW[i >> 6][i & 63] = g_lin_W[i];
    for (int bb = b4; bb < BB; bb += 4) sq[bb][d] = query_emb[r_index[bb] * 64 + d];
    __syncthreads();
    for (int s = 0; s < SS; ++s) {
        for (int bb = b4; bb < BB; bb += 4) st[bb][d] = sq[bb][d] + g_time_emb[g_time[s] * 64 + d];
        __syncthreads();
        for (int bb = b4; bb < BB; bb += 4) {
            float acc = g_lin_b[d];
            #pragma unroll
            for (int k = 0; k < 64; ++k) acc += st[bb][k] * sW[k][d];
            sq[bb][d] = acc;
        }
        __syncthreads();
    }
    int p0 = blockIdx.x * 2048;
    for (int p = p0 + tid; p < p0 + 2048; p += 256) {
        int c = p & 127;
        int bt = p >> 7;
        int b = bt / HLENN, t = bt % HLENN;
        float v = (c < 64) ? feature[(size_t)history_poi[b * HLENN + t] * 64 + c]
                           : sq[b][c - 64];
        xseq[p] = v + hte[p];
    }
}

// qkv for 4 rows per block; 384 threads (thread = output col)
__global__ void qkv4_kernel(const float* __restrict__ xseq, const float* __restrict__ Wqkv,
                            float* __restrict__ qkvb) {
    __shared__ float sx[4][128];
    int tid = threadIdx.x;
    int row0 = blockIdx.x * 4;
    for (int i = tid; i < 512; i += 384) sx[i >> 7][i & 127] = xseq[row0 * 128 + i];
    __syncthreads();
    float a0 = 0.f, a1 = 0.f, a2 = 0.f, a3 = 0.f;
    #pragma unroll 8
    for (int k = 0; k < 128; ++k) {
        float w = Wqkv[k * 384 + tid];
        a0 += sx[0][k] * w; a1 += sx[1][k] * w; a2 += sx[2][k] * w; a3 += sx[3][k] * w;
    }
    qkvb[(row0 + 0) * 384 + tid] = a0;
    qkvb[(row0 + 1) * 384 + tid] = a1;
    qkvb[(row0 + 2) * 384 + tid] = a2;
    qkvb[(row0 + 3) * 384 + tid] = a3;
}

// attention per (b, head): 16 blocks, 256 threads
__global__ void attn_kernel(const float* __restrict__ qkv, float* __restrict__ attnout) {
    int b = blockIdx.x >> 1, h = blockIdx.x & 1;
    __shared__ float sq[HLENN][64], sk[HLENN][64], sv[HLENN][64];
    __shared__ float ss[HLENN][HLENN];
    for (int i = threadIdx.x; i < HLENN * 64; i += 256) {
        int t = i >> 6, d = i & 63;
        const float* base = qkv + (size_t)(b * HLENN + t) * 384 + h * 64 + d;
        sq[t][d] = base[0];
        sk[t][d] = base[128];
        sv[t][d] = base[256];
    }
    __syncthreads();
    for (int p = threadIdx.x; p < HLENN * HLENN; p += 256) {
        int i = p / HLENN, j = p % HLENN;
        float acc = 0.f;
        #pragma unroll 8
        for (int d = 0; d < 64; ++d) acc += sq[i][d] * sk[j][d];
        ss[i][j] = acc * 0.125f;
    }
    __syncthreads();
    if (threadIdx.x < HLENN) {
        int i = threadIdx.x;
        float m = -1e30f;
        for (int j = 0; j < HLENN; ++j) m = fmaxf(m, ss[i][j]);
        float sum = 0.f;
        for (int j = 0; j < HLENN; ++j) { float e = expf(ss[i][j] - m); ss[i][j] = e; sum += e; }
        float inv = 1.f / sum;
        for (int j = 0; j < HLENN; ++j) ss[i][j] *= inv;
    }
    __syncthreads();
    for (int p = threadIdx.x; p < HLENN * 64; p += 256) {
        int i = p >> 6, d = p & 63;
        float acc = 0.f;
        for (int j = 0; j < HLENN; ++j) acc += ss[i][j] * sv[j][d];
        attnout[(size_t)(b * HLENN + i) * 128 + h * 64 + d] = acc;
    }
}

// out = LN(resid + aout @ Wo), 4 rows/block, 512 threads
__global__ void addLN4_kernel(const float* __restrict__ aout, const float* __restrict__ Wo,
                              const float* __restrict__ ln, float* __restrict__ xseq) {
    __shared__ float sa[4][128];
    __shared__ float sred[4][128];
    int tid = threadIdx.x;
    int r = tid >> 7, c = tid & 127;
    int row0 = blockIdx.x * 4;
    sa[r][c] = aout[(row0 + r) * 128 + c];
    __syncthreads();
    float acc = xseq[(row0 + r) * 128 + c];
    #pragma unroll 8
    for (int k = 0; k < 128; ++k) acc += sa[r][k] * Wo[k * 128 + c];
    sred[r][c] = acc; __syncthreads();
    for (int off = 64; off > 0; off >>= 1) { if (c < off) sred[r][c] += sred[r][c + off]; __syncthreads(); }
    float mean = sred[r][0] * (1.f / 128.f);
    __syncthreads();
    float dx = acc - mean;
    sred[r][c] = dx * dx; __syncthreads();
    for (int off = 64; off > 0; off >>= 1) { if (c < off) sred[r][c] += sred[r][c + off]; __syncthreads(); }
    float var = sred[r][0] * (1.f / 128.f);
    xseq[(row0 + r) * 128 + c] = dx * rsqrtf(var + 1e-5f) * ln[c] + ln[128 + c];
}

// fused ff1 + relu + ff2 + residual + LN, 4 rows/block, 512 threads
__global__ void ffLN4_kernel(const float* __restrict__ xin, const float* __restrict__ W1,
                             const float* __restrict__ b1, const float* __restrict__ W2,
                             const float* __restrict__ b2, const float* __restrict__ ln,
                             float* __restrict__ xout) {
    __shared__ float sx[4][128];
    __shared__ float sh[4][512];
    __shared__ float spart[4][4][128];
    __shared__ float sred[4][128];
    int tid = threadIdx.x;
    int row0 = blockIdx.x * 4;
    { int r = tid >> 7, c = tid & 127; sx[r][c] = xin[(row0 + r) * 128 + c]; }
    __syncthreads();
    {
        float bb = b1[tid];
        float a0 = bb, a1 = bb, a2 = bb, a3 = bb;
        #pragma unroll 8
        for (int k = 0; k < 128; ++k) {
            float w = W1[k * 512 + tid];
            a0 += sx[0][k] * w; a1 += sx[1][k] * w; a2 += sx[2][k] * w; a3 += sx[3][k] * w;
        }
        sh[0][tid] = fmaxf(a0, 0.f); sh[1][tid] = fmaxf(a1, 0.f);
        sh[2][tid] = fmaxf(a2, 0.f); sh[3][tid] = fmaxf(a3, 0.f);
    }
    __syncthreads();
    int kc = tid >> 7, c = tid & 127;
    float p0 = 0.f, p1 = 0.f, p2 = 0.f, p3 = 0.f;
    #pragma unroll 8
    for (int kk = 0; kk < 128; ++kk) {
        int k = kc * 128 + kk;
        float w = W2[k * 128 + c];
        p0 += sh[0][k] * w; p1 += sh[1][k] * w; p2 += sh[2][k] * w; p3 += sh[3][k] * w;
    }
    spart[kc][0][c] = p0; spart[kc][1][c] = p1; spart[kc][2][c] = p2; spart[kc][3][c] = p3;
    __syncthreads();
    int r = kc;
    float acc = b2[c] + spart[0][r][c] + spart[1][r][c] + spart[2][r][c] + spart[3][r][c] + sx[r][c];
    sred[r][c] = acc; __syncthreads();
    for (int off = 64; off > 0; off >>= 1) { if (c < off) sred[r][c] += sred[r][c + off]; __syncthreads(); }
    float mean = sred[r][0] * (1.f / 128.f);
    __syncthreads();
    float dx = acc - mean;
    sred[r][c] = dx * dx; __syncthreads();
    for (int off = 64; off > 0; off >>= 1) { if (c < off) sred[r][c] += sred[r][c + off]; __syncthreads(); }
    float var = sred[r][0] * (1.f / 128.f);
    xout[(row0 + r) * 128 + c] = dx * rsqrtf(var + 1e-5f) * ln[c] + ln[128 + c];
}

// score with the sequence-mean folded in: threads 64..191 each compute their
// flab column from xseq directly (50 L2-resident loads).
__global__ __launch_bounds__(192) void score_kernel(
        const float* __restrict__ feature, const float* __restrict__ xseq,
        const int* __restrict__ t_index,
        const float* __restrict__ W1, const float* __restrict__ b1,
        const float* __restrict__ W2, const float* __restrict__ b2,
        float* __restrict__ score) {
    int b = blockIdx.x / KK, k = blockIdx.x % KK;
    __shared__ float sf[192];
    __shared__ float sred[192];
    int j = threadIdx.x;
    float v;
    if (j < 64) {
        int t = t_index[b * KK + k];
        v = feature[(size_t)t * 64 + j];
    } else {
        int c = j - 64;
        float s = 0.f;
        #pragma unroll
        for (int t = 0; t < HLENN; ++t) s += xseq[(b * HLENN + t) * 128 + c];
        v = s * (1.f / HLENN);
    }
    sf[j] = v;
    __syncthreads();
    float acc = b1[j];
    #pragma unroll 8
    for (int i = 0; i < 192; ++i) acc += sf[i] * W1[i * 192 + j];
    float h = fmaxf(acc, 0.f);
    sred[j] = h * W2[j];
    __syncthreads();
    if (j < 64) sred[j] += sred[j + 64] + sred[j + 128];
    __syncthreads();
    for (int off = 32; off > 0; off >>= 1) { if (j < off) sred[j] += sred[j + off]; __syncthreads(); }
    if (j == 0) score[b * KK + k] = sred[0] + b2[0];
}

// ---------------------------------------------------------------------------
extern "C" void kernel_launch(void* const* d_in, const int* in_sizes, int n_in,
                              void* d_out, int out_size, void* d_ws, size_t ws_size,
                              hipStream_t stream) {
    const float* poi_emb   = (const float*)d_in[0];
    const float* query_emb = (const float*)d_in[1];
    const float* gate_W    = (const float*)d_in[2];
    const float* gate_b    = (const float*)d_in[3];
    const float* gnn_rel   = (const float*)d_in[4];   // [2,24,64]
    const float* gnn_W     = (const float*)d_in[5];   // [2,128,64]
    const float* gnn_b     = (const float*)d_in[6];   // [2,64]
    const float* g_time_emb= (const float*)d_in[7];
    const float* g_lin_W   = (const float*)d_in[8];
    const float* g_lin_b   = (const float*)d_in[9];
    const float* tf_Wqkv   = (const float*)d_in[10];
    const float* tf_Wo     = (const float*)d_in[11];
    const float* tf_ln1    = (const float*)d_in[12];
    const float* tf_ln2    = (const float*)d_in[13];
    const float* tf_W1     = (const float*)d_in[14];
    const float* tf_b1     = (const float*)d_in[15];
    const float* tf_W2     = (const float*)d_in[16];
    const float* tf_b2     = (const float*)d_in[17];
    const float* mlp_W1    = (const float*)d_in[18];
    const float* mlp_b1    = (const float*)d_in[19];
    const float* mlp_W2    = (const float*)d_in[20];
    const float* mlp_b2    = (const float*)d_in[21];
    const float* hte       = (const float*)d_in[22];
    const int* edge_src    = (const int*)d_in[23];
    const int* edge_dst    = (const int*)d_in[24];
    const int* edge_type   = (const int*)d_in[25];
    const int* r_index     = (const int*)d_in[27];    // h_index (26) unused
    const int* t_index     = (const int*)d_in[28];
    const int* history_poi = (const int*)d_in[29];
    const int* g_time      = (const int*)d_in[30];

    float* ws = (float*)d_ws;
    float* xA    = ws;                         // 20000*64
    float* xB    = xA + 1280000;
    float* initb = xB + 1280000;
    float* y     = initb + 1280000;            // 20032*64
    float* z     = y + 20032 * 64;
    float* xseq  = z + 20032 * 64;             // 51200
    float* qkvb  = xseq + 51200;               // 153600
    float* aout  = qkvb + 153600;              // 51200
    int* hist    = (int*)(aout + 51200);       // 3*NN
    int* deg     = hist + 3 * NN;              // 3*NN
    int* rowptr  = deg + 3 * NN;               // 3*(NN+1)
    int* cursor  = rowptr + 3 * (NN + 1);      // 3*NN
    int* colp    = cursor + 3 * NN;            // 3*EE

    // ---- CSR build + degree for all 3 snapshots (wide kernels) ----
    hipMemsetAsync(hist, 0, 2 * 3 * NN * sizeof(int), stream);   // hist + deg contiguous
    {
        dim3 g((EE + 255) / 256, 3);
        hist_kernel<<<g, 256, 0, stream>>>(edge_src, edge_dst, hist, deg);
        scan_kernel<<<3, 1024, 0, stream>>>(hist, rowptr, cursor);
        place_kernel<<<g, 256, 0, stream>>>(edge_src, edge_dst, edge_type, cursor, colp);
    }

    // ---- GNN over snapshots (batch-independent), wide split kernels ----
    for (int s = 0; s < SS; ++s) {
        const int* rp = rowptr + s * (NN + 1);
        const int* cp = colp + s * EE;
        init_kernel<<<NN / 4, 256, 0, stream>>>(poi_emb, deg + s * NN, gate_W, gate_b,
                                                xA, initb, s > 0 ? 1 : 0);
        const float* Wt0 = gnn_W;                 // layer0 rows 0..63 (agg part)
        const float* Wb0 = gnn_W + 64 * 64;       // layer0 rows 64..127 (init part)
        const float* Wt1 = gnn_W + 128 * 64;
        const float* Wb1 = gnn_W + 128 * 64 + 64 * 64;
        const float* rel0 = gnn_rel;
        const float* rel1 = gnn_rel + 24 * 64;
        dim3 gg(313, 2);
        // layer 0:  y = [init|rel0]@Wt0,  z = init@Wb0
        gemm64_kernel<<<gg, 256, 0, stream>>>(initb, rel0, Wt0, y,
                                              initb, rel0, Wb0, z);
        fin_kernel<<<NN / 16, 256, 0, stream>>>(y, z, rp, cp, gnn_b, xB);
        // layer 1:  y = [x1|rel1]@Wt1,  z = init@Wb1
        gemm64_kernel<<<gg, 256, 0, stream>>>(xB, rel1, Wt1, y,
                                              initb, rel1, Wb1, z);
        fin_kernel<<<NN / 16, 256, 0, stream>>>(y, z, rp, cp, gnn_b + 64, xA);
    }

    // ---- query chain + history gather (merged, 25 blocks) ----
    queryxseq_kernel<<<25, 256, 0, stream>>>(xA, query_emb, r_index, g_time_emb,
                                             g_time, g_lin_W, g_lin_b,
                                             history_poi, hte, xseq);

    // ---- transformer (2 layers on [8,50,128]) — split kernels ----
    for (int l = 0; l < 2; ++l) {
        qkv4_kernel<<<BB * HLENN / 4, 384, 0, stream>>>(xseq, tf_Wqkv + l * 128 * 384, qkvb);
        attn_kernel<<<BB * 2, 256, 0, stream>>>(qkvb, aout);
        addLN4_kernel<<<BB * HLENN / 4, 512, 0, stream>>>(aout, tf_Wo + l * 128 * 128,
                                                          tf_ln1 + l * 256, xseq);
        ffLN4_kernel<<<BB * HLENN / 4, 512, 0, stream>>>(xseq, tf_W1 + l * 128 * 512,
                                                         tf_b1 + l * 512, tf_W2 + l * 512 * 128,
                                                         tf_b2 + l * 128, tf_ln2 + l * 256, xseq);
    }

    // ---- scoring (mean folded in) ----
    score_kernel<<<BB * KK, 192, 0, stream>>>(xA, xseq, t_index,
                                              mlp_W1, mlp_b1, mlp_W2, mlp_b2, (float*)d_out);
}

// Round 11
// 530.687 us; speedup vs baseline: 2.7545x; 1.0053x over previous
//
#include <hip/hip_runtime.h>
#include <hip/hip_bf16.h>
#include <math.h>

#define DD   64
#define DD2  128
#define NN   20000
#define RR   24
#define SS   3
#define EE   60000
#define BB   8
#define KK   101
#define HLENN 50
#define MROWS 20024   // 20000 nodes + 24 appended rel rows

// ---------------------------------------------------------------------------
// histogram by dst (for CSR) + full degree (src+dst counts). Wide: (235,3).
__global__ void hist_kernel(const int* __restrict__ src, const int* __restrict__ dst,
                            int* __restrict__ hist, int* __restrict__ deg) {
    int s = blockIdx.y;
    int e = blockIdx.x * 256 + threadIdx.x;
    if (e < EE) {
        int d0 = dst[s * EE + e], s0 = src[s * EE + e];
        atomicAdd(&hist[s * NN + d0], 1);
        atomicAdd(&deg[s * NN + d0], 1);
        atomicAdd(&deg[s * NN + s0], 1);
    }
}

// exclusive scan of hist -> rowptr (N+1) and cursor copy. One block per snapshot.
__global__ void scan_kernel(const int* __restrict__ hist, int* __restrict__ rowptr,
                            int* __restrict__ cursor) {
    int s = blockIdx.x, t = threadIdx.x;
    const int* h = hist + s * NN;
    int* rp = rowptr + s * (NN + 1);
    int* cur = cursor + s * NN;
    __shared__ int sp[1024];
    int base = t * 20, sum = 0;
    for (int i = 0; i < 20; ++i) { int idx = base + i; if (idx < NN) sum += h[idx]; }
    sp[t] = sum;
    __syncthreads();
    for (int off = 1; off < 1024; off <<= 1) {
        int v = (t >= off) ? sp[t - off] : 0;
        __syncthreads();
        sp[t] += v;
        __syncthreads();
    }
    int run = sp[t] - sum;  // exclusive
    for (int i = 0; i < 20; ++i) {
        int idx = base + i;
        if (idx < NN) { rp[idx] = run; cur[idx] = run; run += h[idx]; }
    }
    if (t == 1023) rp[NN] = sp[1023];
}

// place edges into CSR slots: col[pos] = src | (et<<16). Wide: (235,3).
__global__ void place_kernel(const int* __restrict__ src, const int* __restrict__ dst,
                             const int* __restrict__ et, int* __restrict__ cursor,
                             int* __restrict__ colp) {
    int s = blockIdx.y;
    int e = blockIdx.x * 256 + threadIdx.x;
    if (e < EE) {
        int d0 = dst[s * EE + e];
        int pos = atomicAdd(&cursor[s * NN + d0], 1);
        colp[s * EE + pos] = src[s * EE + e] | (et[s * EE + e] << 16);
    }
}

// init (s=0 only, no gate): init[n,d] = deg[n]*poi[n,d]. 5000 blocks.
__global__ void init_kernel(const float* __restrict__ poi, const int* __restrict__ deg,
                            float* __restrict__ initb) {
    int li = threadIdx.x >> 6, d = threadIdx.x & 63;
    int node = blockIdx.x * 4 + li;
    initb[(size_t)node * 64 + d] = (float)deg[node] * poi[(size_t)node * 64 + d];
}

// batched C[y] = [A|Ar] @ B[y] for up to 3 (B,C) pairs selected by blockIdx.y.
// 64x64 tile per block, 256 threads, 4x4 micro-tile.
__global__ void gemm64_kernel(const float* __restrict__ A0, const float* __restrict__ Ar,
                              const float* __restrict__ B0, const float* __restrict__ B1,
                              const float* __restrict__ B2,
                              float* __restrict__ C0, float* __restrict__ C1,
                              float* __restrict__ C2) {
    const float* B = blockIdx.y == 0 ? B0 : (blockIdx.y == 1 ? B1 : B2);
    float* C       = blockIdx.y == 0 ? C0 : (blockIdx.y == 1 ? C1 : C2);
    __shared__ float sA[64][68];
    __shared__ float sB[64][68];
    int tid = threadIdx.x;
    int row0 = blockIdx.x * 64;
    for (int i = tid; i < 64 * 16; i += 256) {
        int r = i >> 4, cq = i & 15;
        int row = row0 + r;
        float4 v = make_float4(0.f, 0.f, 0.f, 0.f);
        if (row < NN)         v = *(const float4*)(A0 + (size_t)row * 64 + cq * 4);
        else if (row < MROWS) v = *(const float4*)(Ar + (size_t)(row - NN) * 64 + cq * 4);
        *(float4*)&sA[r][cq * 4] = v;
        float4 w = *(const float4*)(B + (size_t)r * 64 + cq * 4);
        *(float4*)&sB[r][cq * 4] = w;
    }
    __syncthreads();
    int tr = tid >> 4, tc = tid & 15;
    float acc[4][4] = {{0.f}};
    #pragma unroll 16
    for (int k = 0; k < 64; ++k) {
        float4 b4 = *(const float4*)&sB[k][tc * 4];
        float a0 = sA[tr * 4 + 0][k];
        float a1 = sA[tr * 4 + 1][k];
        float a2 = sA[tr * 4 + 2][k];
        float a3 = sA[tr * 4 + 3][k];
        acc[0][0] += a0 * b4.x; acc[0][1] += a0 * b4.y; acc[0][2] += a0 * b4.z; acc[0][3] += a0 * b4.w;
        acc[1][0] += a1 * b4.x; acc[1][1] += a1 * b4.y; acc[1][2] += a1 * b4.z; acc[1][3] += a1 * b4.w;
        acc[2][0] += a2 * b4.x; acc[2][1] += a2 * b4.y; acc[2][2] += a2 * b4.z; acc[2][3] += a2 * b4.w;
        acc[3][0] += a3 * b4.x; acc[3][1] += a3 * b4.y; acc[3][2] += a3 * b4.z; acc[3][3] += a3 * b4.w;
    }
    #pragma unroll
    for (int i = 0; i < 4; ++i) {
        int row = row0 + tr * 4 + i;
        if (row < MROWS) {
            *(float4*)(C + (size_t)row * 64 + tc * 4) = make_float4(acc[i][0], acc[i][1], acc[i][2], acc[i][3]);
        }
    }
}

// layer-0 fin: x_out[n] = relu(z[n] + b + sum_in-edges(y[src]+relW[et])). 1250 blocks.
__global__ void fin_kernel(const float* __restrict__ y, const float* __restrict__ z,
                           const int* __restrict__ rowptr, const int* __restrict__ colp,
                           const float* __restrict__ bias, float* __restrict__ xout) {
    __shared__ float srelW[24][64];
    int tid = threadIdx.x;
    for (int i = tid; i < 24 * 64; i += 256) srelW[i >> 6][i & 63] = y[(size_t)NN * 64 + i];
    int d = tid & 63, w = tid >> 6;
    float bb = bias[d];
    __syncthreads();
    int base = blockIdx.x * 16 + w * 4;
    for (int n = 0; n < 4; ++n) {
        int node = base + n;
        float acc = z[(size_t)node * 64 + d] + bb;
        int e0 = rowptr[node], e1 = rowptr[node + 1];
        for (int e = e0; e < e1; ++e) {
            int pack = colp[e];
            acc += y[(size_t)(pack & 0xFFFF) * 64 + d] + srelW[pack >> 16][d];
        }
        xout[(size_t)node * 64 + d] = fmaxf(acc, 0.f);
    }
}

// layer-1 fin fused with the gated init of the NEXT snapshot (if do_gate):
// x = relu(z2 + b + gather); g = sigmoid(x@gate_W+gb);
// init_next = deg_next*poi*g + (1-g)*x. 1250 blocks.
__global__ void finGate_kernel(const float* __restrict__ y, const float* __restrict__ z,
                               const int* __restrict__ rowptr, const int* __restrict__ colp,
                               const float* __restrict__ bias,
                               const float* __restrict__ gate_W, const float* __restrict__ gate_b,
                               const int* __restrict__ deg_next, const float* __restrict__ poi,
                               float* __restrict__ xout, float* __restrict__ init_next,
                               int do_gate) {
    __shared__ float srelW[24][64];
    __shared__ float sX[16][64];
    __shared__ float sGW[64][64];
    int tid = threadIdx.x;
    for (int i = tid; i < 24 * 64; i += 256) srelW[i >> 6][i & 63] = y[(size_t)NN * 64 + i];
    if (do_gate) {
        for (int i = tid; i < 64 * 64; i += 256) sGW[i >> 6][i & 63] = gate_W[i];
    }
    int d = tid & 63, w = tid >> 6;
    float bb = bias[d];
    __syncthreads();
    int base = blockIdx.x * 16 + w * 4;
    for (int n = 0; n < 4; ++n) {
        int node = base + n;
        float acc = z[(size_t)node * 64 + d] + bb;
        int e0 = rowptr[node], e1 = rowptr[node + 1];
        for (int e = e0; e < e1; ++e) {
            int pack = colp[e];
            acc += y[(size_t)(pack & 0xFFFF) * 64 + d] + srelW[pack >> 16][d];
        }
        float v = fmaxf(acc, 0.f);
        xout[(size_t)node * 64 + d] = v;
        sX[w * 4 + n][d] = v;
    }
    if (do_gate) {
        __syncthreads();
        float gb = gate_b[d];
        for (int n = 0; n < 4; ++n) {
            int ln = w * 4 + n;
            int node = base + n;
            float acc = gb;
            #pragma unroll
            for (int k = 0; k < 64; ++k) acc += sX[ln][k] * sGW[k][d];
            float g = 1.f / (1.f + expf(-acc));
            float iv = (float)deg_next[node] * poi[(size_t)node * 64 + d];
            init_next[(size_t)node * 64 + d] = iv * g + (1.f - g) * sX[ln][d];
        }
    }
}

// ---------------------------------------------------------------------------
// Merged query chain + xseq build. 25 blocks x 256 threads.
__global__ void queryxseq_kernel(const float* __restrict__ feature,
                                 const float* __restrict__ query_emb,
                                 const int* __restrict__ r_index,
                                 const float* __restrict__ g_time_emb,
                                 const int* __restrict__ g_time,
                                 const float* __restrict__ g_lin_W,
                                 const float* __restrict__ g_lin_b,
                                 const int* __restrict__ history_poi,
                                 const float* __restrict__ hte,
                                 float* __restrict__ xseq) {
    __shared__ float sW[64][64];
    __shared__ float sq[8][64];
    __shared__ float st[8][64];
    int tid = threadIdx.x;
    int b4 = tid >> 6, d = tid & 63;
    for (int i = tid; i < 64 * 64; i += 256) sW[i >> 6][i & 63] = g_lin_W[i];
    for (int bb = b4; bb < BB; bb += 4) sq[bb][d] = query_emb[r_index[bb] * 64 + d];
    __syncthreads();
    for (int s = 0; s < SS; ++s) {
        for (int bb = b4; bb < BB; bb += 4) st[bb][d] = sq[bb][d] + g_time_emb[g_time[s] * 64 + d];
        __syncthreads();
        for (int bb = b4; bb < BB; bb += 4) {
            float acc = g_lin_b[d];
            #pragma unroll
            for (int k = 0; k < 64; ++k) acc += st[bb][k] * sW[k][d];
            sq[bb][d] = acc;
        }
        __syncthreads();
    }
    int p0 = blockIdx.x * 2048;
    for (int p = p0 + tid; p < p0 + 2048; p += 256) {
        int c = p & 127;
        int bt = p >> 7;
        int b = bt / HLENN, t = bt % HLENN;
        float v = (c < 64) ? feature[(size_t)history_poi[b * HLENN + t] * 64 + c]
                           : sq[b][c - 64];
        xseq[p] = v + hte[p];
    }
}

// qkv for 4 rows per block; 384 threads (layer 0 entry only)
__global__ void qkv4_kernel(const float* __restrict__ xseq, const float* __restrict__ Wqkv,
                            float* __restrict__ qkvb) {
    __shared__ float sx[4][128];
    int tid = threadIdx.x;
    int row0 = blockIdx.x * 4;
    for (int i = tid; i < 512; i += 384) sx[i >> 7][i & 127] = xseq[row0 * 128 + i];
    __syncthreads();
    float a0 = 0.f, a1 = 0.f, a2 = 0.f, a3 = 0.f;
    #pragma unroll 8
    for (int k = 0; k < 128; ++k) {
        float w = Wqkv[k * 384 + tid];
        a0 += sx[0][k] * w; a1 += sx[1][k] * w; a2 += sx[2][k] * w; a3 += sx[3][k] * w;
    }
    qkvb[(row0 + 0) * 384 + tid] = a0;
    qkvb[(row0 + 1) * 384 + tid] = a1;
    qkvb[(row0 + 2) * 384 + tid] = a2;
    qkvb[(row0 + 3) * 384 + tid] = a3;
}

// attention per (b, head): 16 blocks, 256 threads
__global__ void attn_kernel(const float* __restrict__ qkv, float* __restrict__ attnout) {
    int b = blockIdx.x >> 1, h = blockIdx.x & 1;
    __shared__ float sq[HLENN][64], sk[HLENN][64], sv[HLENN][64];
    __shared__ float ss[HLENN][HLENN];
    for (int i = threadIdx.x; i < HLENN * 64; i += 256) {
        int t = i >> 6, d = i & 63;
        const float* base = qkv + (size_t)(b * HLENN + t) * 384 + h * 64 + d;
        sq[t][d] = base[0];
        sk[t][d] = base[128];
        sv[t][d] = base[256];
    }
    __syncthreads();
    for (int p = threadIdx.x; p < HLENN * HLENN; p += 256) {
        int i = p / HLENN, j = p % HLENN;
        float acc = 0.f;
        #pragma unroll 8
        for (int d = 0; d < 64; ++d) acc += sq[i][d] * sk[j][d];
        ss[i][j] = acc * 0.125f;
    }
    __syncthreads();
    if (threadIdx.x < HLENN) {
        int i = threadIdx.x;
        float m = -1e30f;
        for (int j = 0; j < HLENN; ++j) m = fmaxf(m, ss[i][j]);
        float sum = 0.f;
        for (int j = 0; j < HLENN; ++j) { float e = expf(ss[i][j] - m); ss[i][j] = e; sum += e; }
        float inv = 1.f / sum;
        for (int j = 0; j < HLENN; ++j) ss[i][j] *= inv;
    }
    __syncthreads();
    for (int p = threadIdx.x; p < HLENN * 64; p += 256) {
        int i = p >> 6, d = p & 63;
        float acc = 0.f;
        for (int j = 0; j < HLENN; ++j) acc += ss[i][j] * sv[j][d];
        attnout[(size_t)(b * HLENN + i) * 128 + h * 64 + d] = acc;
    }
}

// Merged addLN + ff1 + ff2 + LN2 (+ optional next-layer qkv). 4 rows/block, 512 thr.
template<int DO_QKV>
__global__ __launch_bounds__(512) void tfout_kernel(
        const float* __restrict__ aout, const float* __restrict__ Wo,
        const float* __restrict__ ln1,
        const float* __restrict__ W1, const float* __restrict__ b1,
        const float* __restrict__ W2, const float* __restrict__ b2,
        const float* __restrict__ ln2,
        float* __restrict__ xseq,
        const float* __restrict__ Wqkv_next, float* __restrict__ qkvb) {
    __shared__ float sa[4][128];
    __shared__ float sx[4][128];
    __shared__ float sh[4][512];
    __shared__ float spart[4][4][128];
    __shared__ float sred[4][128];
    __shared__ float sfin[4][128];
    int tid = threadIdx.x;
    int row0 = blockIdx.x * 4;
    int r = tid >> 7, c = tid & 127;
    sa[r][c] = aout[(row0 + r) * 128 + c];
    __syncthreads();
    float acc = xseq[(row0 + r) * 128 + c];
    #pragma unroll 8
    for (int k = 0; k < 128; ++k) acc += sa[r][k] * Wo[k * 128 + c];
    sred[r][c] = acc; __syncthreads();
    for (int off = 64; off > 0; off >>= 1) { if (c < off) sred[r][c] += sred[r][c + off]; __syncthreads(); }
    float mean = sred[r][0] * (1.f / 128.f);
    __syncthreads();
    float dx = acc - mean;
    sred[r][c] = dx * dx; __syncthreads();
    for (int off = 64; off > 0; off >>= 1) { if (c < off) sred[r][c] += sred[r][c + off]; __syncthreads(); }
    float var = sred[r][0] * (1.f / 128.f);
    sx[r][c] = dx * rsqrtf(var + 1e-5f) * ln1[c] + ln1[128 + c];
    __syncthreads();
    // ff1
    {
        float bb = b1[tid];
        float a0 = bb, a1 = bb, a2 = bb, a3 = bb;
        #pragma unroll 8
        for (int k = 0; k < 128; ++k) {
            float w = W1[k * 512 + tid];
            a0 += sx[0][k] * w; a1 += sx[1][k] * w; a2 += sx[2][k] * w; a3 += sx[3][k] * w;
        }
        sh[0][tid] = fmaxf(a0, 0.f); sh[1][tid] = fmaxf(a1, 0.f);
        sh[2][tid] = fmaxf(a2, 0.f); sh[3][tid] = fmaxf(a3, 0.f);
    }
    __syncthreads();
    // ff2 partials
    int kc = tid >> 7;
    float p0 = 0.f, p1 = 0.f, p2 = 0.f, p3 = 0.f;
    #pragma unroll 8
    for (int kk = 0; kk < 128; ++kk) {
        int k = kc * 128 + kk;
        float w = W2[k * 128 + c];
        p0 += sh[0][k] * w; p1 += sh[1][k] * w; p2 += sh[2][k] * w; p3 += sh[3][k] * w;
    }
    spart[kc][0][c] = p0; spart[kc][1][c] = p1; spart[kc][2][c] = p2; spart[kc][3][c] = p3;
    __syncthreads();
    float acc2 = b2[c] + spart[0][r][c] + spart[1][r][c] + spart[2][r][c] + spart[3][r][c] + sx[r][c];
    sred[r][c] = acc2; __syncthreads();
    for (int off = 64; off > 0; off >>= 1) { if (c < off) sred[r][c] += sred[r][c + off]; __syncthreads(); }
    float mean2 = sred[r][0] * (1.f / 128.f);
    __syncthreads();
    float dx2 = acc2 - mean2;
    sred[r][c] = dx2 * dx2; __syncthreads();
    for (int off = 64; off > 0; off >>= 1) { if (c < off) sred[r][c] += sred[r][c + off]; __syncthreads(); }
    float var2 = sred[r][0] * (1.f / 128.f);
    float out = dx2 * rsqrtf(var2 + 1e-5f) * ln2[c] + ln2[128 + c];
    xseq[(row0 + r) * 128 + c] = out;
    if (DO_QKV) {
        sfin[r][c] = out;
        __syncthreads();
        if (tid < 384) {
            float a0 = 0.f, a1 = 0.f, a2 = 0.f, a3 = 0.f;
            #pragma unroll 8
            for (int k = 0; k < 128; ++k) {
                float w = Wqkv_next[k * 384 + tid];
                a0 += sfin[0][k] * w; a1 += sfin[1][k] * w; a2 += sfin[2][k] * w; a3 += sfin[3][k] * w;
            }
            qkvb[(row0 + 0) * 384 + tid] = a0;
            qkvb[(row0 + 1) * 384 + tid] = a1;
            qkvb[(row0 + 2) * 384 + tid] = a2;
            qkvb[(row0 + 3) * 384 + tid] = a3;
        }
    }
}

// score with the sequence-mean folded in.
__global__ __launch_bounds__(192) void score_kernel(
        const float* __restrict__ feature, const float* __restrict__ xseq,
        const int* __restrict__ t_index,
        const float* __restrict__ W1, const float* __restrict__ b1,
        const float* __restrict__ W2, const float* __restrict__ b2,
        float* __restrict__ score) {
    int b = blockIdx.x / KK, k = blockIdx.x % KK;
    __shared__ float sf[192];
    __shared__ float sred[192];
    int j = threadIdx.x;
    float v;
    if (j < 64) {
        int t = t_index[b * KK + k];
        v = feature[(size_t)t * 64 + j];
    } else {
        int c = j - 64;
        float s = 0.f;
        #pragma unroll
        for (int t = 0; t < HLENN; ++t) s += xseq[(b * HLENN + t) * 128 + c];
        v = s * (1.f / HLENN);
    }
    sf[j] = v;
    __syncthreads();
    float acc = b1[j];
    #pragma unroll 8
    for (int i = 0; i < 192; ++i) acc += sf[i] * W1[i * 192 + j];
    float h = fmaxf(acc, 0.f);
    sred[j] = h * W2[j];
    __syncthreads();
    if (j < 64) sred[j] += sred[j + 64] + sred[j + 128];
    __syncthreads();
    for (int off = 32; off > 0; off >>= 1) { if (j < off) sred[j] += sred[j + off]; __syncthreads(); }
    if (j == 0) score[b * KK + k] = sred[0] + b2[0];
}

// ---------------------------------------------------------------------------
extern "C" void kernel_launch(void* const* d_in, const int* in_sizes, int n_in,
                              void* d_out, int out_size, void* d_ws, size_t ws_size,
                              hipStream_t stream) {
    const float* poi_emb   = (const float*)d_in[0];
    const float* query_emb = (const float*)d_in[1];
    const float* gate_W    = (const float*)d_in[2];
    const float* gate_b    = (const float*)d_in[3];
    const float* gnn_rel   = (const float*)d_in[4];   // [2,24,64]
    const float* gnn_W     = (const float*)d_in[5];   // [2,128,64]
    const float* gnn_b     = (const float*)d_in[6];   // [2,64]
    const float* g_time_emb= (const float*)d_in[7];
    const float* g_lin_W   = (const float*)d_in[8];
    const float* g_lin_b   = (const float*)d_in[9];
    const float* tf_Wqkv   = (const float*)d_in[10];
    const float* tf_Wo     = (const float*)d_in[11];
    const float* tf_ln1    = (const float*)d_in[12];
    const float* tf_ln2    = (const float*)d_in[13];
    const float* tf_W1     = (const float*)d_in[14];
    const float* tf_b1     = (const float*)d_in[15];
    const float* tf_W2     = (const float*)d_in[16];
    const float* tf_b2     = (const float*)d_in[17];
    const float* mlp_W1    = (const float*)d_in[18];
    const float* mlp_b1    = (const float*)d_in[19];
    const float* mlp_W2    = (const float*)d_in[20];
    const float* mlp_b2    = (const float*)d_in[21];
    const float* hte       = (const float*)d_in[22];
    const int* edge_src    = (const int*)d_in[23];
    const int* edge_dst    = (const int*)d_in[24];
    const int* edge_type   = (const int*)d_in[25];
    const int* r_index     = (const int*)d_in[27];    // h_index (26) unused
    const int* t_index     = (const int*)d_in[28];
    const int* history_poi = (const int*)d_in[29];
    const int* g_time      = (const int*)d_in[30];

    float* ws = (float*)d_ws;
    float* xA    = ws;                         // 20000*64
    float* xB    = xA + 1280000;
    float* initb = xB + 1280000;
    float* y     = initb + 1280000;            // 20032*64 (both layers)
    float* z     = y + 20032 * 64;             // layer-0 z
    float* z2    = z + 20032 * 64;             // layer-1 z (computed early)
    float* xseq  = z2 + 20032 * 64;            // 51200
    float* qkvb  = xseq + 51200;               // 153600
    float* aout  = qkvb + 153600;              // 51200
    int* hist    = (int*)(aout + 51200);       // 3*NN
    int* deg     = hist + 3 * NN;              // 3*NN
    int* rowptr  = deg + 3 * NN;               // 3*(NN+1)
    int* cursor  = rowptr + 3 * (NN + 1);      // 3*NN
    int* colp    = cursor + 3 * NN;            // 3*EE

    const float* Wt0  = gnn_W;                 // layer0 rows 0..63 (agg part)
    const float* Wb0  = gnn_W + 64 * 64;       // layer0 rows 64..127 (init part)
    const float* Wt1  = gnn_W + 128 * 64;
    const float* Wb1  = gnn_W + 128 * 64 + 64 * 64;
    const float* rel0 = gnn_rel;
    const float* rel1 = gnn_rel + 24 * 64;

    // ---- CSR build + degree for all 3 snapshots (wide kernels) ----
    hipMemsetAsync(hist, 0, 2 * 3 * NN * sizeof(int), stream);   // hist + deg contiguous
    {
        dim3 g((EE + 255) / 256, 3);
        hist_kernel<<<g, 256, 0, stream>>>(edge_src, edge_dst, hist, deg);
        scan_kernel<<<3, 1024, 0, stream>>>(hist, rowptr, cursor);
        place_kernel<<<g, 256, 0, stream>>>(edge_src, edge_dst, edge_type, cursor, colp);
    }

    // ---- GNN over snapshots (batch-independent) ----
    init_kernel<<<NN / 4, 256, 0, stream>>>(poi_emb, deg, initb);   // s=0, no gate
    for (int s = 0; s < SS; ++s) {
        const int* rp = rowptr + s * (NN + 1);
        const int* cp = colp + s * EE;
        // layer 0 GEMMs + hoisted layer-1 z2 (all depend only on initb):
        //   y = [init|rel0]@Wt0, z = init@Wb0, z2 = init@Wb1
        gemm64_kernel<<<dim3(313, 3), 256, 0, stream>>>(initb, rel0,
                                                        Wt0, Wb0, Wb1, y, z, z2);
        fin_kernel<<<NN / 16, 256, 0, stream>>>(y, z, rp, cp, gnn_b, xB);
        // layer 1: y = [x1|rel1]@Wt1 only
        gemm64_kernel<<<dim3(313, 1), 256, 0, stream>>>(xB, rel1,
                                                        Wt1, Wt1, Wt1, y, y, y);
        // layer-1 fin + gated init of next snapshot (skipped for the last)
        finGate_kernel<<<NN / 16, 256, 0, stream>>>(
            y, z2, rp, cp, gnn_b + 64, gate_W, gate_b,
            deg + (s + 1 < SS ? (s + 1) * NN : 0), poi_emb,
            xA, initb, s + 1 < SS ? 1 : 0);
    }

    // ---- query chain + history gather (merged, 25 blocks) ----
    queryxseq_kernel<<<25, 256, 0, stream>>>(xA, query_emb, r_index, g_time_emb,
                                             g_time, g_lin_W, g_lin_b,
                                             history_poi, hte, xseq);

    // ---- transformer: qkv0 -> attn0 -> tfout0(+qkv1) -> attn1 -> tfout1 ----
    qkv4_kernel<<<BB * HLENN / 4, 384, 0, stream>>>(xseq, tf_Wqkv, qkvb);
    attn_kernel<<<BB * 2, 256, 0, stream>>>(qkvb, aout);
    tfout_kernel<1><<<BB * HLENN / 4, 512, 0, stream>>>(
        aout, tf_Wo, tf_ln1, tf_W1, tf_b1, tf_W2, tf_b2, tf_ln2,
        xseq, tf_Wqkv + 128 * 384, qkvb);
    attn_kernel<<<BB * 2, 256, 0, stream>>>(qkvb, aout);
    tfout_kernel<0><<<BB * HLENN / 4, 512, 0, stream>>>(
        aout, tf_Wo + 128 * 128, tf_ln1 + 256, tf_W1 + 128 * 512, tf_b1 + 512,
        tf_W2 + 512 * 128, tf_b2 + 128, tf_ln2 + 256,
        xseq, nullptr, nullptr);

    // ---- scoring (mean folded in) ----
    score_kernel<<<BB * KK, 192, 0, stream>>>(xA, xseq, t_index,
                                              mlp_W1, mlp_b1, mlp_W2, mlp_b2, (float*)d_out);
}